// Round 11
// baseline (1165.034 us; speedup 1.0000x reference)
//
#include <hip/hip_runtime.h>
#include <math.h>

typedef short bf16x8 __attribute__((ext_vector_type(8)));
typedef float f32x4 __attribute__((ext_vector_type(4)));
typedef _Float16 h16x8 __attribute__((ext_vector_type(8)));
typedef _Float16 h16x4 __attribute__((ext_vector_type(4)));
typedef _Float16 h16x2 __attribute__((ext_vector_type(2)));

static __device__ __forceinline__ float wred_sum(float v){
  #pragma unroll
  for (int o = 32; o > 0; o >>= 1) v += __shfl_xor(v, o, 64);
  return v;
}

static __device__ __forceinline__ unsigned short f2bf(float x){
  union { float f; unsigned int u; } c; c.f = x;
  unsigned int u = c.u;
  return (unsigned short)((u + 0x7FFFu + ((u >> 16) & 1u)) >> 16);
}

// ---------------- prep ----------------
__global__ void prep_kernel(const float* __restrict__ x, const float* __restrict__ ea_in,
                            float* __restrict__ hx, float* __restrict__ ea,
                            int nx, int ne){
  int i = blockIdx.x * 256 + threadIdx.x;
  if (i < nx) hx[i] = logf(x[i] + 1.f);
  if (i < ne) ea[i] = logf(ea_in[i] + 1.f);
}

// ---------------- CSR build ----------------
__global__ void zero_kernel(int* __restrict__ c, int n){
  int i = blockIdx.x * 256 + threadIdx.x;
  if (i < n) c[i] = 0;
}

__global__ void hist_kernel(const int* __restrict__ dst, int* __restrict__ counts, int E){
  int i = blockIdx.x * 256 + threadIdx.x;
  if (i < E) atomicAdd(&counts[dst[i]], 1);
}

// wave-shfl hierarchical scan
__global__ __launch_bounds__(1024) void scan_kernel(const int* __restrict__ counts,
                                                    int* __restrict__ row_ptr,
                                                    int* __restrict__ cursor, int N){
  __shared__ int woff[16];
  __shared__ int carry_s;
  int t = threadIdx.x, lane = t & 63, wid = t >> 6;
  if (t == 0) carry_s = 0;
  __syncthreads();
  for (int base = 0; base < N; base += 1024){
    int i = base + t;
    int v = (i < N) ? counts[i] : 0;
    int incl = v;
    #pragma unroll
    for (int o = 1; o < 64; o <<= 1){
      int tmp = __shfl_up(incl, o, 64);
      if (lane >= o) incl += tmp;
    }
    if (lane == 63) woff[wid] = incl;
    __syncthreads();
    if (t < 16){
      int w = woff[t];
      int inc2 = w;
      #pragma unroll
      for (int o = 1; o < 16; o <<= 1){
        int tmp = __shfl_up(inc2, o, 16);
        if (t >= o) inc2 += tmp;
      }
      woff[t] = inc2 - w;
    }
    __syncthreads();
    int ex = carry_s + woff[wid] + incl - v;
    if (i < N){ row_ptr[i] = ex; cursor[i] = ex; }
    __syncthreads();
    if (t == 1023) carry_s = ex + v;
    __syncthreads();
  }
  if (t == 0) row_ptr[N] = carry_s;
}

__global__ void scatter_kernel(const int* __restrict__ src, const int* __restrict__ dst,
                               const float* __restrict__ ea,
                               int* __restrict__ cursor,
                               int* __restrict__ src_csr, float* __restrict__ ea_csr, int E){
  int i = blockIdx.x * 256 + threadIdx.x;
  if (i < E){
    int p = atomicAdd(&cursor[dst[i]], 1);
    src_csr[p] = src[i];
    *(float4*)&ea_csr[(size_t)p * 4] = *(const float4*)&ea[(size_t)i * 4];
  }
}

// ---------------- head helper ----------------
__global__ void wlscale_kernel(const float* __restrict__ Wl, const float* __restrict__ bl,
                               const float* __restrict__ scale, float* __restrict__ wlsc){
  int c = threadIdx.x;
  float s = 0.f;
  #pragma unroll
  for (int j = 0; j < 8; j++) s += Wl[c * 8 + j] * scale[j];
  wlsc[c] = s;
  if (c == 0){
    float b = 0.f;
    #pragma unroll
    for (int j = 0; j < 8; j++) b += bl[j] * scale[j];
    wlsc[256] = b;
  }
}

// ---------------- weight pack (bf16 W^T for MFMA) ----------------
__global__ __launch_bounds__(256) void pack_w_kernel(
    const float* __restrict__ Wq, const float* __restrict__ Wk,
    const float* __restrict__ Wv, const float* __restrict__ Ws,
    unsigned short* __restrict__ Wp)
{
  __shared__ float t[32][33];
  int l   = blockIdx.z;
  int k0  = blockIdx.x * 32;
  int n0g = blockIdx.y * 32;
  int w   = n0g >> 8;
  int n0  = n0g & 255;
  const float* W = ((w == 0) ? Wq : (w == 1) ? Wk : (w == 2) ? Wv : Ws) + (size_t)l * 65536;
  int rr = threadIdx.x >> 3;
  int cc = (threadIdx.x & 7) * 4;
  float4 vv = *(const float4*)&W[(size_t)(k0 + rr) * 256 + n0 + cc];
  t[rr][cc + 0] = vv.x; t[rr][cc + 1] = vv.y; t[rr][cc + 2] = vv.z; t[rr][cc + 3] = vv.w;
  __syncthreads();
  ushort4 o;
  o.x = f2bf(t[cc + 0][rr]);
  o.y = f2bf(t[cc + 1][rr]);
  o.z = f2bf(t[cc + 2][rr]);
  o.w = f2bf(t[cc + 3][rr]);
  *(ushort4*)&Wp[(size_t)l * 262144 + (size_t)(n0g + rr) * 256 + k0 + cc] = o;
}

__global__ void pack_b_kernel(const float* __restrict__ bq, const float* __restrict__ bk,
                              const float* __restrict__ bv, const float* __restrict__ bs,
                              float* __restrict__ bp){
  int i = blockIdx.x * 256 + threadIdx.x;
  if (i < 15 * 256){
    int l = i >> 8, n = i & 255;
    bp[l * 1024 + 0   + n] = bq[i];
    bp[l * 1024 + 256 + n] = bk[i];
    bp[l * 1024 + 512 + n] = bv[i];
    bp[l * 1024 + 768 + n] = bs[i];
  }
}

// ---------------- pack Wqe ----------------
__global__ __launch_bounds__(256) void pack_wqe_kernel(
    const float* __restrict__ Wq, const float* __restrict__ We,
    const float* __restrict__ bq, float* __restrict__ Wqe, float* __restrict__ bqe)
{
  __shared__ float We_s[1024];
  int l = blockIdx.x;
  for (int i = threadIdx.x; i < 1024; i += 256) We_s[i] = We[(size_t)l * 1024 + i];
  __syncthreads();
  int k = threadIdx.x;
  const float* wrow = Wq + (size_t)l * 65536 + (size_t)k * 256;
  float s0 = 0.f, s1 = 0.f, s2 = 0.f, s3 = 0.f;
  for (int c = 0; c < 256; c++){
    float wv = wrow[c];
    s0 += wv * We_s[c];
    s1 += wv * We_s[256 + c];
    s2 += wv * We_s[512 + c];
    s3 += wv * We_s[768 + c];
  }
  float4 o; o.x = s0; o.y = s1; o.z = s2; o.w = s3;
  *(float4*)&Wqe[((size_t)l * 256 + k) * 4] = o;
  if (k < 4){
    float b = 0.f;
    for (int c = 0; c < 256; c++) b += bq[l * 256 + c] * We_s[k * 256 + c];
    bqe[l * 4 + k] = b;
  }
}

// ---------------- qwe for conv1 ----------------
__global__ __launch_bounds__(256) void qwe1_kernel(const _Float16* __restrict__ qkvh,
                                                   const float* __restrict__ We1,
                                                   float* __restrict__ qwe, int N){
  __shared__ float We_s[1024];
  for (int i = threadIdx.x; i < 1024; i += 256) We_s[i] = We1[i];
  __syncthreads();
  int wid = threadIdx.x >> 6, lane = threadIdx.x & 63;
  int n = blockIdx.x * 4 + wid;
  if (n >= N) return;
  int c0 = lane * 4;
  h16x4 qr = *(const h16x4*)&qkvh[(size_t)n * 768 + c0];
  float q0 = (float)qr[0], q1 = (float)qr[1], q2 = (float)qr[2], q3 = (float)qr[3];
  float4 o;
  #pragma unroll
  for (int j = 0; j < 4; j++){
    float s = q0 * We_s[j * 256 + c0] + q1 * We_s[j * 256 + c0 + 1]
            + q2 * We_s[j * 256 + c0 + 2] + q3 * We_s[j * 256 + c0 + 3];
    s = wred_sum(s);
    if (j == 0) o.x = s; else if (j == 1) o.y = s; else if (j == 2) o.z = s; else o.w = s;
  }
  if (lane == 0) *(float4*)&qwe[(size_t)n * 4] = o;
}

// ---------------- conv1 GEMMs ----------------
__global__ __launch_bounds__(256) void gemm1_kernel(
    const float* __restrict__ A,
    const float* __restrict__ W0, const float* __restrict__ W1,
    const float* __restrict__ W2, const float* __restrict__ W3,
    const float* __restrict__ B0, const float* __restrict__ B1,
    const float* __restrict__ B2, const float* __restrict__ B3,
    _Float16* __restrict__ qkvh, _Float16* __restrict__ slh, int N)
{
  __shared__ float As[64][16];
  int nb = blockIdx.x * 64;
  {
    int row = nb + (threadIdx.x >> 2);
    int qq = (threadIdx.x & 3) * 4;
    float4 a = make_float4(0.f, 0.f, 0.f, 0.f);
    if (row < N) a = *(const float4*)&A[row * 16 + qq];
    *(float4*)&As[threadIdx.x >> 2][qq] = a;
  }
  __syncthreads();
  int col = threadIdx.x;
  #pragma unroll
  for (int w = 0; w < 4; w++){
    const float* W  = (w == 0) ? W0 : (w == 1) ? W1 : (w == 2) ? W2 : W3;
    const float* Bi = (w == 0) ? B0 : (w == 1) ? B1 : (w == 2) ? B2 : B3;
    float wr[16];
    #pragma unroll
    for (int kk = 0; kk < 16; kk++) wr[kk] = W[kk * 256 + col];
    float bias = Bi[col];
    for (int r = 0; r < 64; r++){
      int row = nb + r;
      if (row >= N) break;
      float acc = bias;
      #pragma unroll
      for (int kk = 0; kk < 16; kk++) acc += As[r][kk] * wr[kk];
      if (w < 3) qkvh[(size_t)row * 768 + w * 256 + col] = (_Float16)acc;
      else       slh[(size_t)row * 256 + col] = (_Float16)acc;
    }
  }
}

// ---------------- main MFMA GEMM (XCD-swizzled, LDS-staged epilogue) ----------------
__global__ __launch_bounds__(256, 3) void gemm_mfma_kernel(
    const unsigned short* __restrict__ A,
    const unsigned short* __restrict__ Wp,
    const float* __restrict__ bp,
    _Float16* __restrict__ qkvh,
    _Float16* __restrict__ slh,
    int M)
{
  __shared__ unsigned short lds[2 * 128 * 64];
  unsigned short* ldsA = lds;
  unsigned short* ldsB = lds + 128 * 64;
  const int tid  = threadIdx.x;
  const int wave = tid >> 6, lane = tid & 63;
  const int wm = wave >> 1, wn = wave & 1;
  const int rt  = (int)gridDim.x;
  const int lin = (int)blockIdx.x + rt * (int)blockIdx.y;
  const int gt  = (lin & 7) * rt + (lin >> 3);
  const int m0 = (gt >> 3) * 128;
  const int n0 = (gt & 7) * 128;

  f32x4 acc[4][4] = {};

  const int srow  = lane >> 3;
  const int sc16  = lane & 7;
  const int skgrp = sc16 ^ (srow & 7);

  for (int k0 = 0; k0 < 256; k0 += 64){
    #pragma unroll
    for (int it = 0; it < 4; ++it){
      int lrow = wave * 32 + it * 8;
      const unsigned short* gA = A + (size_t)(m0 + lrow + srow) * 256 + k0 + skgrp * 8;
      __builtin_amdgcn_global_load_lds((const __attribute__((address_space(1))) unsigned int*)gA,
          (__attribute__((address_space(3))) unsigned int*)(ldsA + lrow * 64), 16, 0, 0);
      const unsigned short* gB = Wp + (size_t)(n0 + lrow + srow) * 256 + k0 + skgrp * 8;
      __builtin_amdgcn_global_load_lds((const __attribute__((address_space(1))) unsigned int*)gB,
          (__attribute__((address_space(3))) unsigned int*)(ldsB + lrow * 64), 16, 0, 0);
    }
    __syncthreads();

    bf16x8 af[4][2], bfr[4][2];
    #pragma unroll
    for (int mb = 0; mb < 4; ++mb){
      int r = wm * 64 + mb * 16 + (lane & 15);
      #pragma unroll
      for (int ks = 0; ks < 2; ++ks){
        int kg = ks * 4 + (lane >> 4);
        af[mb][ks] = *(const bf16x8*)&ldsA[r * 64 + ((kg ^ (r & 7)) * 8)];
      }
    }
    #pragma unroll
    for (int nb = 0; nb < 4; ++nb){
      int r = wn * 64 + nb * 16 + (lane & 15);
      #pragma unroll
      for (int ks = 0; ks < 2; ++ks){
        int kg = ks * 4 + (lane >> 4);
        bfr[nb][ks] = *(const bf16x8*)&ldsB[r * 64 + ((kg ^ (r & 7)) * 8)];
      }
    }
    #pragma unroll
    for (int mb = 0; mb < 4; ++mb){
      #pragma unroll
      for (int nb = 0; nb < 4; ++nb){
        acc[mb][nb] = __builtin_amdgcn_mfma_f32_16x16x32_bf16(af[mb][0], bfr[nb][0], acc[mb][nb], 0, 0, 0);
        acc[mb][nb] = __builtin_amdgcn_mfma_f32_16x16x32_bf16(af[mb][1], bfr[nb][1], acc[mb][nb], 0, 0, 0);
      }
    }
    __syncthreads();
  }

  // epilogue via swizzled LDS f16 tile: conflict-free writes, coalesced 16B stores
  _Float16* lt = (_Float16*)lds;   // [128][128], col ^ ((row>>2)&3)<<4
  #pragma unroll
  for (int nb = 0; nb < 4; ++nb){
    int col = wn * 64 + nb * 16 + (lane & 15);
    float bias = bp[n0 + col];
    #pragma unroll
    for (int mb = 0; mb < 4; ++mb){
      #pragma unroll
      for (int r4 = 0; r4 < 4; ++r4){
        int row = wm * 64 + mb * 16 + (lane >> 4) * 4 + r4;
        lt[row * 128 + (col ^ (((row >> 2) & 3) << 4))] = (_Float16)(acc[mb][nb][r4] + bias);
      }
    }
  }
  __syncthreads();
  int tr = tid >> 4;
  int tc = (tid & 15) * 8;
  if (n0 < 768){
    #pragma unroll
    for (int it = 0; it < 8; ++it){
      int row = tr + it * 16;
      int grow = m0 + row;
      if (grow < M){
        h16x8 v8 = *(const h16x8*)&lt[row * 128 + (tc ^ (((row >> 2) & 3) << 4))];
        *(h16x8*)&qkvh[(size_t)grow * 768 + n0 + tc] = v8;
      }
    }
  } else {
    #pragma unroll
    for (int it = 0; it < 8; ++it){
      int row = tr + it * 16;
      int grow = m0 + row;
      if (grow < M){
        h16x8 v8 = *(const h16x8*)&lt[row * 128 + (tc ^ (((row >> 2) & 3) << 4))];
        *(h16x8*)&slh[(size_t)grow * 256 + (n0 - 768) + tc] = v8;
      }
    }
  }
}

// ---------------- fused attention aggregation (+head on last layer) ----------------
// GRID-STRIDE over nodes: each wave handles ~4 nodes sequentially so cross-node
// independent loads overlap the current node's softmax/epilogue VALU chain.
__global__ __launch_bounds__(256) void agg_kernel(
    const _Float16* __restrict__ qkvh,
    const _Float16* __restrict__ slh,
    const float* __restrict__ qwe,
    const float* __restrict__ ea_csr,
    const int* __restrict__ src_csr,
    const float* __restrict__ We,
    const float* __restrict__ Wqe_next,
    const float* __restrict__ bqe_next,
    const int* __restrict__ row_ptr,
    const float* __restrict__ h_in, float* __restrict__ h_out,
    unsigned short* __restrict__ h2b, float* __restrict__ qwe_out,
    const float* __restrict__ wlsc, float* __restrict__ out,
    int RESID, int LAST, int N)
{
  int wid = threadIdx.x >> 6, lane = threadIdx.x & 63;
  int c0 = lane * 4;
  int glane = lane >> 3;          // edge slot 0..7
  int slane = lane & 7;           // channel group (32 ch each)
  union hu { h16x8 v; h16x2 p[4]; };
  int stride = (int)gridDim.x * 4;

  for (int n = blockIdx.x * 4 + wid; n < N; n += stride){
    int e0 = row_ptr[n], e1 = row_ptr[n + 1];
    float4 qwe4 = *(const float4*)&qwe[(size_t)n * 4];
    h16x4 slv4 = *(const h16x4*)&slh[(size_t)n * 256 + c0];
    float4 hp = make_float4(0.f, 0.f, 0.f, 0.f);
    if (RESID) hp = *(const float4*)&h_in[(size_t)n * 256 + c0];
    const _Float16* qrow = qkvh + (size_t)n * 768 + slane * 32;
    hu qf[4];
    #pragma unroll
    for (int u = 0; u < 4; ++u) qf[u].v = *(const h16x8*)(qrow + u * 8);

    float m = -INFINITY, ssum = 0.f;
    float a0 = 0.f, a1 = 0.f, a2 = 0.f, a3 = 0.f;
    float ec0 = 0.f, ec1 = 0.f, ec2 = 0.f, ec3 = 0.f;

    for (int base = e0; base < e1; base += 8){
      int cnt = min(8, e1 - base);
      int eg = base + ((glane < cnt) ? glane : (cnt - 1));
      int sg = src_csr[eg];
      int sj[8];
      #pragma unroll
      for (int j = 0; j < 8; ++j) sj[j] = __shfl(sg, j << 3, 64);
      float4 eag = *(const float4*)&ea_csr[(size_t)eg * 4];
      const _Float16* krow = qkvh + (size_t)sg * 768 + 256 + slane * 32;
      float dot = 0.f;
      #pragma unroll
      for (int u = 0; u < 4; ++u){
        hu kf;
        kf.v = *(const h16x8*)(krow + u * 8);
        #pragma unroll
        for (int pp = 0; pp < 4; ++pp){
#if __has_builtin(__builtin_amdgcn_fdot2)
          dot = __builtin_amdgcn_fdot2(qf[u].p[pp], kf.p[pp], dot, false);
#else
          dot += (float)qf[u].p[pp][0] * (float)kf.p[pp][0] + (float)qf[u].p[pp][1] * (float)kf.p[pp][1];
#endif
        }
      }
      #pragma unroll
      for (int o = 1; o < 8; o <<= 1) dot += __shfl_xor(dot, o, 64);
      float alpha_g = (dot + qwe4.x * eag.x + qwe4.y * eag.y + qwe4.z * eag.z + qwe4.w * eag.w) * 0.0625f;
      float aj[8];
      #pragma unroll
      for (int j = 0; j < 8; ++j){
        aj[j] = __shfl(alpha_g, j << 3, 64);
        if (j >= cnt) aj[j] = -INFINITY;
      }
      float mc = fmaxf(fmaxf(fmaxf(aj[0], aj[1]), fmaxf(aj[2], aj[3])),
                       fmaxf(fmaxf(aj[4], aj[5]), fmaxf(aj[6], aj[7])));
      float mn = fmaxf(m, mc);
      float corr = expf(m - mn);
      float wj[8];
      float wtot = 0.f;
      #pragma unroll
      for (int j = 0; j < 8; ++j){
        wj[j] = (j < cnt) ? expf(aj[j] - mn) : 0.f;
        wtot += wj[j];
      }
      ssum = ssum * corr + wtot;
      a0 *= corr; a1 *= corr; a2 *= corr; a3 *= corr;
      ec0 *= corr; ec1 *= corr; ec2 *= corr; ec3 *= corr;
      m = mn;
      #pragma unroll
      for (int j = 0; j < 8; ++j){
        if (j < cnt){
          h16x4 vr = *(const h16x4*)&qkvh[(size_t)sj[j] * 768 + 512 + c0];
          float4 er = *(const float4*)&ea_csr[(size_t)(base + j) * 4];
          a0 += wj[j] * (float)vr[0];
          a1 += wj[j] * (float)vr[1];
          a2 += wj[j] * (float)vr[2];
          a3 += wj[j] * (float)vr[3];
          ec0 += wj[j] * er.x;
          ec1 += wj[j] * er.y;
          ec2 += wj[j] * er.z;
          ec3 += wj[j] * er.w;
        }
      }
    }

    float inv = 1.f / (ssum + 1e-16f);
    float4 W0 = *(const float4*)&We[0 * 256 + c0];
    float4 W1 = *(const float4*)&We[1 * 256 + c0];
    float4 W2 = *(const float4*)&We[2 * 256 + c0];
    float4 W3 = *(const float4*)&We[3 * 256 + c0];
    float emb0 = ec0 * W0.x + ec1 * W1.x + ec2 * W2.x + ec3 * W3.x;
    float emb1 = ec0 * W0.y + ec1 * W1.y + ec2 * W2.y + ec3 * W3.y;
    float emb2 = ec0 * W0.z + ec1 * W1.z + ec2 * W2.z + ec3 * W3.z;
    float emb3 = ec0 * W0.w + ec1 * W1.w + ec2 * W2.w + ec3 * W3.w;
    float y0 = (a0 + emb0) * inv + (float)slv4[0];
    float y1 = (a1 + emb1) * inv + (float)slv4[1];
    float y2 = (a2 + emb2) * inv + (float)slv4[2];
    float y3 = (a3 + emb3) * inv + (float)slv4[3];
    float o0 = hp.x + y0, o1 = hp.y + y1, o2 = hp.z + y2, o3 = hp.w + y3;
    if (LAST){
      float4 wv = *(const float4*)&wlsc[c0];
      float pp = o0 * wv.x + o1 * wv.y + o2 * wv.z + o3 * wv.w;
      pp = wred_sum(pp);
      if (lane == 0) out[n] = pp * (1.f / sqrtf(15.f)) + wlsc[256];
      continue;
    }
    float4 ho; ho.x = o0; ho.y = o1; ho.z = o2; ho.w = o3;
    *(float4*)&h_out[(size_t)n * 256 + c0] = ho;
    float mean = wred_sum(o0 + o1 + o2 + o3) * (1.f / 256.f);
    float d0 = o0 - mean, d1 = o1 - mean, d2 = o2 - mean, d3 = o3 - mean;
    float var = wred_sum(d0 * d0 + d1 * d1 + d2 * d2 + d3 * d3) * (1.f / 255.f);
    float invstd = 1.f / sqrtf(var);
    float t0 = fmaxf(o0 * invstd, 0.f);
    float t1 = fmaxf(o1 * invstd, 0.f);
    float t2 = fmaxf(o2 * invstd, 0.f);
    float t3 = fmaxf(o3 * invstd, 0.f);
    ushort4 hb;
    hb.x = f2bf(t0); hb.y = f2bf(t1); hb.z = f2bf(t2); hb.w = f2bf(t3);
    *(ushort4*)&h2b[(size_t)n * 256 + c0] = hb;
    if (Wqe_next){
      float4 g0 = *(const float4*)&Wqe_next[(c0 + 0) * 4];
      float4 g1 = *(const float4*)&Wqe_next[(c0 + 1) * 4];
      float4 g2 = *(const float4*)&Wqe_next[(c0 + 2) * 4];
      float4 g3 = *(const float4*)&Wqe_next[(c0 + 3) * 4];
      float s0 = t0 * g0.x + t1 * g1.x + t2 * g2.x + t3 * g3.x;
      float s1 = t0 * g0.y + t1 * g1.y + t2 * g2.y + t3 * g3.y;
      float s2 = t0 * g0.z + t1 * g1.z + t2 * g2.z + t3 * g3.z;
      float s3 = t0 * g0.w + t1 * g1.w + t2 * g2.w + t3 * g3.w;
      s0 = wred_sum(s0); s1 = wred_sum(s1); s2 = wred_sum(s2); s3 = wred_sum(s3);
      if (lane == 0){
        float4 bq4 = *(const float4*)bqe_next;
        float4 o; o.x = s0 + bq4.x; o.y = s1 + bq4.y; o.z = s2 + bq4.z; o.w = s3 + bq4.w;
        *(float4*)&qwe_out[(size_t)n * 4] = o;
      }
    }
  }
}

// ---------------- launch ----------------
extern "C" void kernel_launch(void* const* d_in, const int* in_sizes, int n_in,
                              void* d_out, int out_size, void* d_ws, size_t ws_size,
                              hipStream_t stream)
{
  const float* x     = (const float*)d_in[0];
  const int*   eidx  = (const int*)d_in[1];
  const float* Wq1 = (const float*)d_in[3];  const float* bq1 = (const float*)d_in[4];
  const float* Wk1 = (const float*)d_in[5];  const float* bk1 = (const float*)d_in[6];
  const float* Wv1 = (const float*)d_in[7];  const float* bv1 = (const float*)d_in[8];
  const float* We1 = (const float*)d_in[9];
  const float* Ws1 = (const float*)d_in[10]; const float* bs1 = (const float*)d_in[11];
  const float* Wq = (const float*)d_in[12];  const float* bq = (const float*)d_in[13];
  const float* Wk = (const float*)d_in[14];  const float* bk = (const float*)d_in[15];
  const float* Wv = (const float*)d_in[16];  const float* bv = (const float*)d_in[17];
  const float* We = (const float*)d_in[18];
  const float* Ws = (const float*)d_in[19];  const float* bs = (const float*)d_in[20];
  const float* Wl = (const float*)d_in[21];  const float* bl = (const float*)d_in[22];
  const float* scale = (const float*)d_in[23];
  (void)n_in; (void)ws_size;

  int N = in_sizes[0] / 16;
  int E = in_sizes[2] / 4;
  int Mpad = (N + 127) & ~127;
  float* out = (float*)d_out;
  (void)out_size;

  char* p = (char*)d_ws;
  auto alloc = [&](size_t bytes) -> char* {
    char* r = p; p += (bytes + 255) & ~(size_t)255; return r;
  };
  float* hx   = (float*)alloc((size_t)N * 16 * 4);
  float* ea   = (float*)alloc((size_t)E * 4 * 4);
  float* h    = (float*)alloc((size_t)N * 256 * 4);
  unsigned short* h2b = (unsigned short*)alloc((size_t)Mpad * 256 * 2);
  _Float16* qkvh = (_Float16*)alloc((size_t)N * 768 * 2);
  _Float16* slh  = (_Float16*)alloc((size_t)N * 256 * 2);
  float* qwe  = (float*)alloc((size_t)N * 4 * 4);
  float* ea_csr = (float*)alloc((size_t)E * 4 * 4);
  int* src_csr  = (int*)alloc((size_t)E * 4);
  unsigned short* Wp  = (unsigned short*)alloc((size_t)15 * 1024 * 256 * 2);
  float* bp   = (float*)alloc((size_t)15 * 1024 * 4);
  float* Wqe  = (float*)alloc((size_t)15 * 256 * 4 * 4);
  float* bqe  = (float*)alloc((size_t)15 * 4 * 4);
  float* wlsc = (float*)alloc(257 * 4);
  int* counts  = (int*)alloc((size_t)N * 4);
  int* cursor  = (int*)alloc((size_t)N * 4);
  int* row_ptr = (int*)alloc(((size_t)N + 1) * 4);

  const int* srcp = eidx;
  const int* dstp = eidx + E;

  int nx = N * 16, ne = E * 4;
  int big = nx > ne ? nx : ne;

  zero_kernel<<<(N + 255) / 256, 256, 0, stream>>>(counts, N);
  prep_kernel<<<(big + 255) / 256, 256, 0, stream>>>(x, (const float*)d_in[2], hx, ea, nx, ne);
  hist_kernel<<<(E + 255) / 256, 256, 0, stream>>>(dstp, counts, E);
  scan_kernel<<<1, 1024, 0, stream>>>(counts, row_ptr, cursor, N);
  scatter_kernel<<<(E + 255) / 256, 256, 0, stream>>>(srcp, dstp, ea, cursor,
                                                      src_csr, ea_csr, E);
  wlscale_kernel<<<1, 256, 0, stream>>>(Wl, bl, scale, wlsc);
  pack_w_kernel<<<dim3(8, 32, 15), 256, 0, stream>>>(Wq, Wk, Wv, Ws, Wp);
  pack_b_kernel<<<15, 256, 0, stream>>>(bq, bk, bv, bs, bp);
  pack_wqe_kernel<<<15, 256, 0, stream>>>(Wq, We, bq, Wqe, bqe);

  int agg_blocks = 1280;   // 5 blocks/CU target; grid-stride covers all nodes

  // conv1
  gemm1_kernel<<<(N + 63) / 64, 256, 0, stream>>>(hx, Wq1, Wk1, Wv1, Ws1,
                                                  bq1, bk1, bv1, bs1, qkvh, slh, N);
  qwe1_kernel<<<(N + 3) / 4, 256, 0, stream>>>(qkvh, We1, qwe, N);
  agg_kernel<<<agg_blocks, 256, 0, stream>>>(qkvh, slh, qwe, ea_csr, src_csr, We1,
                                             Wqe, bqe, row_ptr,
                                             h, h, h2b, qwe, wlsc, out, 0, 0, N);

  // 15 residual blocks
  for (int l = 0; l < 15; l++){
    gemm_mfma_kernel<<<dim3(Mpad / 128, 8), 256, 0, stream>>>(
        h2b, Wp + (size_t)l * 262144, bp + (size_t)l * 1024, qkvh, slh, N);
    int last = (l == 14);
    const float* wqe_n = (l < 14) ? (Wqe + (size_t)(l + 1) * 1024) : nullptr;
    const float* bqe_n = (l < 14) ? (bqe + (size_t)(l + 1) * 4) : nullptr;
    agg_kernel<<<agg_blocks, 256, 0, stream>>>(qkvh, slh, qwe, ea_csr, src_csr,
                                               We + (size_t)l * 1024,
                                               wqe_n, bqe_n, row_ptr,
                                               h, h, h2b, qwe, wlsc, out, 1, last, N);
  }
}

// Round 12
// 1155.403 us; speedup vs baseline: 1.0083x; 1.0083x over previous
//
#include <hip/hip_runtime.h>
#include <math.h>

typedef short bf16x8 __attribute__((ext_vector_type(8)));
typedef float f32x4 __attribute__((ext_vector_type(4)));
typedef _Float16 h16x8 __attribute__((ext_vector_type(8)));
typedef _Float16 h16x4 __attribute__((ext_vector_type(4)));
typedef _Float16 h16x2 __attribute__((ext_vector_type(2)));

static __device__ __forceinline__ float wred_sum(float v){
  #pragma unroll
  for (int o = 32; o > 0; o >>= 1) v += __shfl_xor(v, o, 64);
  return v;
}

// reduction within a 32-lane half (xor offsets < 32 never cross halves)
static __device__ __forceinline__ float hred_sum(float v){
  #pragma unroll
  for (int o = 16; o > 0; o >>= 1) v += __shfl_xor(v, o, 64);
  return v;
}

static __device__ __forceinline__ unsigned short f2bf(float x){
  union { float f; unsigned int u; } c; c.f = x;
  unsigned int u = c.u;
  return (unsigned short)((u + 0x7FFFu + ((u >> 16) & 1u)) >> 16);
}

// ---------------- prep ----------------
__global__ void prep_kernel(const float* __restrict__ x, const float* __restrict__ ea_in,
                            float* __restrict__ hx, float* __restrict__ ea,
                            int nx, int ne){
  int i = blockIdx.x * 256 + threadIdx.x;
  if (i < nx) hx[i] = logf(x[i] + 1.f);
  if (i < ne) ea[i] = logf(ea_in[i] + 1.f);
}

// ---------------- CSR build ----------------
__global__ void zero_kernel(int* __restrict__ c, int n){
  int i = blockIdx.x * 256 + threadIdx.x;
  if (i < n) c[i] = 0;
}

__global__ void hist_kernel(const int* __restrict__ dst, int* __restrict__ counts, int E){
  int i = blockIdx.x * 256 + threadIdx.x;
  if (i < E) atomicAdd(&counts[dst[i]], 1);
}

// wave-shfl hierarchical scan
__global__ __launch_bounds__(1024) void scan_kernel(const int* __restrict__ counts,
                                                    int* __restrict__ row_ptr,
                                                    int* __restrict__ cursor, int N){
  __shared__ int woff[16];
  __shared__ int carry_s;
  int t = threadIdx.x, lane = t & 63, wid = t >> 6;
  if (t == 0) carry_s = 0;
  __syncthreads();
  for (int base = 0; base < N; base += 1024){
    int i = base + t;
    int v = (i < N) ? counts[i] : 0;
    int incl = v;
    #pragma unroll
    for (int o = 1; o < 64; o <<= 1){
      int tmp = __shfl_up(incl, o, 64);
      if (lane >= o) incl += tmp;
    }
    if (lane == 63) woff[wid] = incl;
    __syncthreads();
    if (t < 16){
      int w = woff[t];
      int inc2 = w;
      #pragma unroll
      for (int o = 1; o < 16; o <<= 1){
        int tmp = __shfl_up(inc2, o, 16);
        if (t >= o) inc2 += tmp;
      }
      woff[t] = inc2 - w;
    }
    __syncthreads();
    int ex = carry_s + woff[wid] + incl - v;
    if (i < N){ row_ptr[i] = ex; cursor[i] = ex; }
    __syncthreads();
    if (t == 1023) carry_s = ex + v;
    __syncthreads();
  }
  if (t == 0) row_ptr[N] = carry_s;
}

__global__ void scatter_kernel(const int* __restrict__ src, const int* __restrict__ dst,
                               const float* __restrict__ ea,
                               int* __restrict__ cursor,
                               int* __restrict__ src_csr, float* __restrict__ ea_csr, int E){
  int i = blockIdx.x * 256 + threadIdx.x;
  if (i < E){
    int p = atomicAdd(&cursor[dst[i]], 1);
    src_csr[p] = src[i];
    *(float4*)&ea_csr[(size_t)p * 4] = *(const float4*)&ea[(size_t)i * 4];
  }
}

// ---------------- head helper ----------------
__global__ void wlscale_kernel(const float* __restrict__ Wl, const float* __restrict__ bl,
                               const float* __restrict__ scale, float* __restrict__ wlsc){
  int c = threadIdx.x;
  float s = 0.f;
  #pragma unroll
  for (int j = 0; j < 8; j++) s += Wl[c * 8 + j] * scale[j];
  wlsc[c] = s;
  if (c == 0){
    float b = 0.f;
    #pragma unroll
    for (int j = 0; j < 8; j++) b += bl[j] * scale[j];
    wlsc[256] = b;
  }
}

// ---------------- weight pack (bf16 W^T for MFMA) ----------------
__global__ __launch_bounds__(256) void pack_w_kernel(
    const float* __restrict__ Wq, const float* __restrict__ Wk,
    const float* __restrict__ Wv, const float* __restrict__ Ws,
    unsigned short* __restrict__ Wp)
{
  __shared__ float t[32][33];
  int l   = blockIdx.z;
  int k0  = blockIdx.x * 32;
  int n0g = blockIdx.y * 32;
  int w   = n0g >> 8;
  int n0  = n0g & 255;
  const float* W = ((w == 0) ? Wq : (w == 1) ? Wk : (w == 2) ? Wv : Ws) + (size_t)l * 65536;
  int rr = threadIdx.x >> 3;
  int cc = (threadIdx.x & 7) * 4;
  float4 vv = *(const float4*)&W[(size_t)(k0 + rr) * 256 + n0 + cc];
  t[rr][cc + 0] = vv.x; t[rr][cc + 1] = vv.y; t[rr][cc + 2] = vv.z; t[rr][cc + 3] = vv.w;
  __syncthreads();
  ushort4 o;
  o.x = f2bf(t[cc + 0][rr]);
  o.y = f2bf(t[cc + 1][rr]);
  o.z = f2bf(t[cc + 2][rr]);
  o.w = f2bf(t[cc + 3][rr]);
  *(ushort4*)&Wp[(size_t)l * 262144 + (size_t)(n0g + rr) * 256 + k0 + cc] = o;
}

__global__ void pack_b_kernel(const float* __restrict__ bq, const float* __restrict__ bk,
                              const float* __restrict__ bv, const float* __restrict__ bs,
                              float* __restrict__ bp){
  int i = blockIdx.x * 256 + threadIdx.x;
  if (i < 15 * 256){
    int l = i >> 8, n = i & 255;
    bp[l * 1024 + 0   + n] = bq[i];
    bp[l * 1024 + 256 + n] = bk[i];
    bp[l * 1024 + 512 + n] = bv[i];
    bp[l * 1024 + 768 + n] = bs[i];
  }
}

// ---------------- pack Wqe ----------------
__global__ __launch_bounds__(256) void pack_wqe_kernel(
    const float* __restrict__ Wq, const float* __restrict__ We,
    const float* __restrict__ bq, float* __restrict__ Wqe, float* __restrict__ bqe)
{
  __shared__ float We_s[1024];
  int l = blockIdx.x;
  for (int i = threadIdx.x; i < 1024; i += 256) We_s[i] = We[(size_t)l * 1024 + i];
  __syncthreads();
  int k = threadIdx.x;
  const float* wrow = Wq + (size_t)l * 65536 + (size_t)k * 256;
  float s0 = 0.f, s1 = 0.f, s2 = 0.f, s3 = 0.f;
  for (int c = 0; c < 256; c++){
    float wv = wrow[c];
    s0 += wv * We_s[c];
    s1 += wv * We_s[256 + c];
    s2 += wv * We_s[512 + c];
    s3 += wv * We_s[768 + c];
  }
  float4 o; o.x = s0; o.y = s1; o.z = s2; o.w = s3;
  *(float4*)&Wqe[((size_t)l * 256 + k) * 4] = o;
  if (k < 4){
    float b = 0.f;
    for (int c = 0; c < 256; c++) b += bq[l * 256 + c] * We_s[k * 256 + c];
    bqe[l * 4 + k] = b;
  }
}

// ---------------- qwe for conv1 ----------------
__global__ __launch_bounds__(256) void qwe1_kernel(const _Float16* __restrict__ qkvh,
                                                   const float* __restrict__ We1,
                                                   float* __restrict__ qwe, int N){
  __shared__ float We_s[1024];
  for (int i = threadIdx.x; i < 1024; i += 256) We_s[i] = We1[i];
  __syncthreads();
  int wid = threadIdx.x >> 6, lane = threadIdx.x & 63;
  int n = blockIdx.x * 4 + wid;
  if (n >= N) return;
  int c0 = lane * 4;
  h16x4 qr = *(const h16x4*)&qkvh[(size_t)n * 768 + c0];
  float q0 = (float)qr[0], q1 = (float)qr[1], q2 = (float)qr[2], q3 = (float)qr[3];
  float4 o;
  #pragma unroll
  for (int j = 0; j < 4; j++){
    float s = q0 * We_s[j * 256 + c0] + q1 * We_s[j * 256 + c0 + 1]
            + q2 * We_s[j * 256 + c0 + 2] + q3 * We_s[j * 256 + c0 + 3];
    s = wred_sum(s);
    if (j == 0) o.x = s; else if (j == 1) o.y = s; else if (j == 2) o.z = s; else o.w = s;
  }
  if (lane == 0) *(float4*)&qwe[(size_t)n * 4] = o;
}

// ---------------- conv1 GEMMs ----------------
__global__ __launch_bounds__(256) void gemm1_kernel(
    const float* __restrict__ A,
    const float* __restrict__ W0, const float* __restrict__ W1,
    const float* __restrict__ W2, const float* __restrict__ W3,
    const float* __restrict__ B0, const float* __restrict__ B1,
    const float* __restrict__ B2, const float* __restrict__ B3,
    _Float16* __restrict__ qkvh, _Float16* __restrict__ slh, int N)
{
  __shared__ float As[64][16];
  int nb = blockIdx.x * 64;
  {
    int row = nb + (threadIdx.x >> 2);
    int qq = (threadIdx.x & 3) * 4;
    float4 a = make_float4(0.f, 0.f, 0.f, 0.f);
    if (row < N) a = *(const float4*)&A[row * 16 + qq];
    *(float4*)&As[threadIdx.x >> 2][qq] = a;
  }
  __syncthreads();
  int col = threadIdx.x;
  #pragma unroll
  for (int w = 0; w < 4; w++){
    const float* W  = (w == 0) ? W0 : (w == 1) ? W1 : (w == 2) ? W2 : W3;
    const float* Bi = (w == 0) ? B0 : (w == 1) ? B1 : (w == 2) ? B2 : B3;
    float wr[16];
    #pragma unroll
    for (int kk = 0; kk < 16; kk++) wr[kk] = W[kk * 256 + col];
    float bias = Bi[col];
    for (int r = 0; r < 64; r++){
      int row = nb + r;
      if (row >= N) break;
      float acc = bias;
      #pragma unroll
      for (int kk = 0; kk < 16; kk++) acc += As[r][kk] * wr[kk];
      if (w < 3) qkvh[(size_t)row * 768 + w * 256 + col] = (_Float16)acc;
      else       slh[(size_t)row * 256 + col] = (_Float16)acc;
    }
  }
}

// ---------------- main MFMA GEMM (XCD-swizzled, LDS-staged epilogue) ----------------
__global__ __launch_bounds__(256, 3) void gemm_mfma_kernel(
    const unsigned short* __restrict__ A,
    const unsigned short* __restrict__ Wp,
    const float* __restrict__ bp,
    _Float16* __restrict__ qkvh,
    _Float16* __restrict__ slh,
    int M)
{
  __shared__ unsigned short lds[2 * 128 * 64];
  unsigned short* ldsA = lds;
  unsigned short* ldsB = lds + 128 * 64;
  const int tid  = threadIdx.x;
  const int wave = tid >> 6, lane = tid & 63;
  const int wm = wave >> 1, wn = wave & 1;
  const int rt  = (int)gridDim.x;
  const int lin = (int)blockIdx.x + rt * (int)blockIdx.y;
  const int gt  = (lin & 7) * rt + (lin >> 3);
  const int m0 = (gt >> 3) * 128;
  const int n0 = (gt & 7) * 128;

  f32x4 acc[4][4] = {};

  const int srow  = lane >> 3;
  const int sc16  = lane & 7;
  const int skgrp = sc16 ^ (srow & 7);

  for (int k0 = 0; k0 < 256; k0 += 64){
    #pragma unroll
    for (int it = 0; it < 4; ++it){
      int lrow = wave * 32 + it * 8;
      const unsigned short* gA = A + (size_t)(m0 + lrow + srow) * 256 + k0 + skgrp * 8;
      __builtin_amdgcn_global_load_lds((const __attribute__((address_space(1))) unsigned int*)gA,
          (__attribute__((address_space(3))) unsigned int*)(ldsA + lrow * 64), 16, 0, 0);
      const unsigned short* gB = Wp + (size_t)(n0 + lrow + srow) * 256 + k0 + skgrp * 8;
      __builtin_amdgcn_global_load_lds((const __attribute__((address_space(1))) unsigned int*)gB,
          (__attribute__((address_space(3))) unsigned int*)(ldsB + lrow * 64), 16, 0, 0);
    }
    __syncthreads();

    bf16x8 af[4][2], bfr[4][2];
    #pragma unroll
    for (int mb = 0; mb < 4; ++mb){
      int r = wm * 64 + mb * 16 + (lane & 15);
      #pragma unroll
      for (int ks = 0; ks < 2; ++ks){
        int kg = ks * 4 + (lane >> 4);
        af[mb][ks] = *(const bf16x8*)&ldsA[r * 64 + ((kg ^ (r & 7)) * 8)];
      }
    }
    #pragma unroll
    for (int nb = 0; nb < 4; ++nb){
      int r = wn * 64 + nb * 16 + (lane & 15);
      #pragma unroll
      for (int ks = 0; ks < 2; ++ks){
        int kg = ks * 4 + (lane >> 4);
        bfr[nb][ks] = *(const bf16x8*)&ldsB[r * 64 + ((kg ^ (r & 7)) * 8)];
      }
    }
    #pragma unroll
    for (int mb = 0; mb < 4; ++mb){
      #pragma unroll
      for (int nb = 0; nb < 4; ++nb){
        acc[mb][nb] = __builtin_amdgcn_mfma_f32_16x16x32_bf16(af[mb][0], bfr[nb][0], acc[mb][nb], 0, 0, 0);
        acc[mb][nb] = __builtin_amdgcn_mfma_f32_16x16x32_bf16(af[mb][1], bfr[nb][1], acc[mb][nb], 0, 0, 0);
      }
    }
    __syncthreads();
  }

  _Float16* lt = (_Float16*)lds;   // [128][128], col ^ ((row>>2)&3)<<4
  #pragma unroll
  for (int nb = 0; nb < 4; ++nb){
    int col = wn * 64 + nb * 16 + (lane & 15);
    float bias = bp[n0 + col];
    #pragma unroll
    for (int mb = 0; mb < 4; ++mb){
      #pragma unroll
      for (int r4 = 0; r4 < 4; ++r4){
        int row = wm * 64 + mb * 16 + (lane >> 4) * 4 + r4;
        lt[row * 128 + (col ^ (((row >> 2) & 3) << 4))] = (_Float16)(acc[mb][nb][r4] + bias);
      }
    }
  }
  __syncthreads();
  int tr = tid >> 4;
  int tc = (tid & 15) * 8;
  if (n0 < 768){
    #pragma unroll
    for (int it = 0; it < 8; ++it){
      int row = tr + it * 16;
      int grow = m0 + row;
      if (grow < M){
        h16x8 v8 = *(const h16x8*)&lt[row * 128 + (tc ^ (((row >> 2) & 3) << 4))];
        *(h16x8*)&qkvh[(size_t)grow * 768 + n0 + tc] = v8;
      }
    }
  } else {
    #pragma unroll
    for (int it = 0; it < 8; ++it){
      int row = tr + it * 16;
      int grow = m0 + row;
      if (grow < M){
        h16x8 v8 = *(const h16x8*)&lt[row * 128 + (tc ^ (((row >> 2) & 3) << 4))];
        *(h16x8*)&slh[(size_t)grow * 256 + (n0 - 768) + tc] = v8;
      }
    }
  }
}

// ---------------- fused attention aggregation: 2 NODES PER WAVE ----------------
// lanes 0-31 -> node A, lanes 32-63 -> node B. 8 edge slots x 4 lanes (64 ch).
// Channel-parallel epilogue: 8 ch/lane, 16B loads/stores.
__global__ __launch_bounds__(256) void agg_kernel(
    const _Float16* __restrict__ qkvh,
    const _Float16* __restrict__ slh,
    const float* __restrict__ qwe,
    const float* __restrict__ ea_csr,
    const int* __restrict__ src_csr,
    const float* __restrict__ We,
    const float* __restrict__ Wqe_next,
    const float* __restrict__ bqe_next,
    const int* __restrict__ row_ptr,
    const _Float16* __restrict__ h_in, _Float16* __restrict__ h_out,
    unsigned short* __restrict__ h2b, float* __restrict__ qwe_out,
    const float* __restrict__ wlsc, float* __restrict__ out,
    int RESID, int LAST, int N, int E)
{
  int wid = threadIdx.x >> 6, lane = threadIdx.x & 63;
  int half = lane >> 5, hl = lane & 31;
  int n = blockIdx.x * 8 + wid * 2 + half;
  bool valid = (n < N);
  int nn = valid ? n : (N - 1);
  int c0 = hl * 8;                // 8 channels per lane
  int glane = hl >> 2;            // edge slot 0..7
  int slane = hl & 3;             // 64-ch quarter within slot
  union hu { h16x8 v; h16x2 p[4]; };

  int e0 = row_ptr[nn], e1 = row_ptr[nn + 1];
  float4 qwe4 = *(const float4*)&qwe[(size_t)nn * 4];
  h16x8 slv = *(const h16x8*)&slh[(size_t)nn * 256 + c0];
  h16x8 hpv = {};
  if (RESID) hpv = *(const h16x8*)&h_in[(size_t)nn * 256 + c0];
  const _Float16* qrow = qkvh + (size_t)nn * 768 + slane * 64;
  hu qf[8];
  #pragma unroll
  for (int u = 0; u < 8; ++u) qf[u].v = *(const h16x8*)(qrow + u * 8);

  float m = -INFINITY, ssum = 0.f;
  float a[8] = {};
  float ec[4] = {};

  // wave-uniform trip count = max of the two halves
  int nch = (e1 - e0 + 7) >> 3;
  int nco = __shfl_xor(nch, 32, 64);
  int ntrip = nch > nco ? nch : nco;

  for (int it = 0; it < ntrip; ++it){
    int base = e0 + it * 8;
    int cnt = e1 - base; if (cnt > 8) cnt = 8;      // may be <= 0 (exhausted half)
    int off = (cnt > 0) ? ((glane < cnt) ? glane : cnt - 1) : 0;
    int eg = base + off;
    if (eg >= E) eg = E - 1;
    int sg = src_csr[eg];
    int sj[8];
    #pragma unroll
    for (int j = 0; j < 8; ++j) sj[j] = __shfl(sg, (half << 5) + (j << 2), 64);
    float4 eag = *(const float4*)&ea_csr[(size_t)eg * 4];
    const _Float16* krow = qkvh + (size_t)sg * 768 + 256 + slane * 64;
    float dot = 0.f;
    #pragma unroll
    for (int u = 0; u < 8; ++u){
      hu kf;
      kf.v = *(const h16x8*)(krow + u * 8);
      #pragma unroll
      for (int pp = 0; pp < 4; ++pp){
#if __has_builtin(__builtin_amdgcn_fdot2)
        dot = __builtin_amdgcn_fdot2(qf[u].p[pp], kf.p[pp], dot, false);
#else
        dot += (float)qf[u].p[pp][0] * (float)kf.p[pp][0] + (float)qf[u].p[pp][1] * (float)kf.p[pp][1];
#endif
      }
    }
    dot += __shfl_xor(dot, 1, 64);
    dot += __shfl_xor(dot, 2, 64);
    float alpha_g = (dot + qwe4.x * eag.x + qwe4.y * eag.y + qwe4.z * eag.z + qwe4.w * eag.w) * 0.0625f;
    float aj[8];
    #pragma unroll
    for (int j = 0; j < 8; ++j){
      aj[j] = __shfl(alpha_g, (half << 5) + (j << 2), 64);
      if (j >= cnt) aj[j] = -INFINITY;
    }
    float mc = fmaxf(fmaxf(fmaxf(aj[0], aj[1]), fmaxf(aj[2], aj[3])),
                     fmaxf(fmaxf(aj[4], aj[5]), fmaxf(aj[6], aj[7])));
    float mn = fmaxf(m, mc);
    float corr = (mn > -INFINITY) ? expf(m - mn) : 0.f;   // exp(-inf)=0 first chunk
    float wj[8];
    float wtot = 0.f;
    #pragma unroll
    for (int j = 0; j < 8; ++j){
      wj[j] = (j < cnt) ? expf(aj[j] - mn) : 0.f;
      wtot += wj[j];
    }
    ssum = ssum * corr + wtot;
    #pragma unroll
    for (int i = 0; i < 8; ++i) a[i] *= corr;
    #pragma unroll
    for (int i = 0; i < 4; ++i) ec[i] *= corr;
    m = mn;
    #pragma unroll
    for (int j = 0; j < 8; ++j){
      if (j < cnt){
        h16x8 vr = *(const h16x8*)&qkvh[(size_t)sj[j] * 768 + 512 + c0];
        float4 er = *(const float4*)&ea_csr[(size_t)(base + j) * 4];
        #pragma unroll
        for (int i = 0; i < 8; ++i) a[i] += wj[j] * (float)vr[i];
        ec[0] += wj[j] * er.x;
        ec[1] += wj[j] * er.y;
        ec[2] += wj[j] * er.z;
        ec[3] += wj[j] * er.w;
      }
    }
  }

  float inv = 1.f / (ssum + 1e-16f);
  float o[8];
  #pragma unroll
  for (int g = 0; g < 2; ++g){
    float4 w0 = *(const float4*)&We[0 * 256 + c0 + g * 4];
    float4 w1 = *(const float4*)&We[1 * 256 + c0 + g * 4];
    float4 w2 = *(const float4*)&We[2 * 256 + c0 + g * 4];
    float4 w3 = *(const float4*)&We[3 * 256 + c0 + g * 4];
    float e0v = ec[0] * w0.x + ec[1] * w1.x + ec[2] * w2.x + ec[3] * w3.x;
    float e1v = ec[0] * w0.y + ec[1] * w1.y + ec[2] * w2.y + ec[3] * w3.y;
    float e2v = ec[0] * w0.z + ec[1] * w1.z + ec[2] * w2.z + ec[3] * w3.z;
    float e3v = ec[0] * w0.w + ec[1] * w1.w + ec[2] * w2.w + ec[3] * w3.w;
    o[g * 4 + 0] = (a[g * 4 + 0] + e0v) * inv + (float)slv[g * 4 + 0] + (RESID ? (float)hpv[g * 4 + 0] : 0.f);
    o[g * 4 + 1] = (a[g * 4 + 1] + e1v) * inv + (float)slv[g * 4 + 1] + (RESID ? (float)hpv[g * 4 + 1] : 0.f);
    o[g * 4 + 2] = (a[g * 4 + 2] + e2v) * inv + (float)slv[g * 4 + 2] + (RESID ? (float)hpv[g * 4 + 2] : 0.f);
    o[g * 4 + 3] = (a[g * 4 + 3] + e3v) * inv + (float)slv[g * 4 + 3] + (RESID ? (float)hpv[g * 4 + 3] : 0.f);
  }

  if (LAST){
    float pp = 0.f;
    #pragma unroll
    for (int i = 0; i < 8; ++i) pp += o[i] * wlsc[c0 + i];
    pp = hred_sum(pp);
    if (hl == 0 && valid) out[n] = pp * (1.f / sqrtf(15.f)) + wlsc[256];
    return;
  }

  if (valid){
    h16x8 ho;
    #pragma unroll
    for (int i = 0; i < 8; ++i) ho[i] = (_Float16)o[i];
    *(h16x8*)&h_out[(size_t)n * 256 + c0] = ho;
  }
  float s = 0.f;
  #pragma unroll
  for (int i = 0; i < 8; ++i) s += o[i];
  float mean = hred_sum(s) * (1.f / 256.f);
  float vv = 0.f;
  #pragma unroll
  for (int i = 0; i < 8; ++i){ float d = o[i] - mean; vv += d * d; }
  float var = hred_sum(vv) * (1.f / 255.f);
  float invstd = 1.f / sqrtf(var);
  float t[8];
  #pragma unroll
  for (int i = 0; i < 8; ++i) t[i] = fmaxf(o[i] * invstd, 0.f);
  if (valid){
    bf16x8 hb;
    #pragma unroll
    for (int i = 0; i < 8; ++i) hb[i] = (short)f2bf(t[i]);
    *(bf16x8*)&h2b[(size_t)n * 256 + c0] = hb;
  }
  if (Wqe_next){
    float s0 = 0.f, s1 = 0.f, s2 = 0.f, s3 = 0.f;
    #pragma unroll
    for (int i = 0; i < 8; ++i){
      float4 g = *(const float4*)&Wqe_next[(c0 + i) * 4];
      s0 += t[i] * g.x; s1 += t[i] * g.y; s2 += t[i] * g.z; s3 += t[i] * g.w;
    }
    s0 = hred_sum(s0); s1 = hred_sum(s1); s2 = hred_sum(s2); s3 = hred_sum(s3);
    if (hl == 0 && valid){
      float4 bq4 = *(const float4*)bqe_next;
      float4 ov; ov.x = s0 + bq4.x; ov.y = s1 + bq4.y; ov.z = s2 + bq4.z; ov.w = s3 + bq4.w;
      *(float4*)&qwe_out[(size_t)n * 4] = ov;
    }
  }
}

// ---------------- launch ----------------
extern "C" void kernel_launch(void* const* d_in, const int* in_sizes, int n_in,
                              void* d_out, int out_size, void* d_ws, size_t ws_size,
                              hipStream_t stream)
{
  const float* x     = (const float*)d_in[0];
  const int*   eidx  = (const int*)d_in[1];
  const float* Wq1 = (const float*)d_in[3];  const float* bq1 = (const float*)d_in[4];
  const float* Wk1 = (const float*)d_in[5];  const float* bk1 = (const float*)d_in[6];
  const float* Wv1 = (const float*)d_in[7];  const float* bv1 = (const float*)d_in[8];
  const float* We1 = (const float*)d_in[9];
  const float* Ws1 = (const float*)d_in[10]; const float* bs1 = (const float*)d_in[11];
  const float* Wq = (const float*)d_in[12];  const float* bq = (const float*)d_in[13];
  const float* Wk = (const float*)d_in[14];  const float* bk = (const float*)d_in[15];
  const float* Wv = (const float*)d_in[16];  const float* bv = (const float*)d_in[17];
  const float* We = (const float*)d_in[18];
  const float* Ws = (const float*)d_in[19];  const float* bs = (const float*)d_in[20];
  const float* Wl = (const float*)d_in[21];  const float* bl = (const float*)d_in[22];
  const float* scale = (const float*)d_in[23];
  (void)n_in; (void)ws_size;

  int N = in_sizes[0] / 16;
  int E = in_sizes[2] / 4;
  int Mpad = (N + 127) & ~127;
  float* out = (float*)d_out;
  (void)out_size;

  char* p = (char*)d_ws;
  auto alloc = [&](size_t bytes) -> char* {
    char* r = p; p += (bytes + 255) & ~(size_t)255; return r;
  };
  float* hx   = (float*)alloc((size_t)N * 16 * 4);
  float* ea   = (float*)alloc((size_t)E * 4 * 4);
  _Float16* hh = (_Float16*)alloc((size_t)N * 256 * 2);
  unsigned short* h2b = (unsigned short*)alloc((size_t)Mpad * 256 * 2);
  _Float16* qkvh = (_Float16*)alloc((size_t)N * 768 * 2);
  _Float16* slh  = (_Float16*)alloc((size_t)N * 256 * 2);
  float* qwe  = (float*)alloc((size_t)N * 4 * 4);
  float* ea_csr = (float*)alloc((size_t)E * 4 * 4);
  int* src_csr  = (int*)alloc((size_t)E * 4);
  unsigned short* Wp  = (unsigned short*)alloc((size_t)15 * 1024 * 256 * 2);
  float* bp   = (float*)alloc((size_t)15 * 1024 * 4);
  float* Wqe  = (float*)alloc((size_t)15 * 256 * 4 * 4);
  float* bqe  = (float*)alloc((size_t)15 * 4 * 4);
  float* wlsc = (float*)alloc(257 * 4);
  int* counts  = (int*)alloc((size_t)N * 4);
  int* cursor  = (int*)alloc((size_t)N * 4);
  int* row_ptr = (int*)alloc(((size_t)N + 1) * 4);

  const int* srcp = eidx;
  const int* dstp = eidx + E;

  int nx = N * 16, ne = E * 4;
  int big = nx > ne ? nx : ne;

  zero_kernel<<<(N + 255) / 256, 256, 0, stream>>>(counts, N);
  prep_kernel<<<(big + 255) / 256, 256, 0, stream>>>(x, (const float*)d_in[2], hx, ea, nx, ne);
  hist_kernel<<<(E + 255) / 256, 256, 0, stream>>>(dstp, counts, E);
  scan_kernel<<<1, 1024, 0, stream>>>(counts, row_ptr, cursor, N);
  scatter_kernel<<<(E + 255) / 256, 256, 0, stream>>>(srcp, dstp, ea, cursor,
                                                      src_csr, ea_csr, E);
  wlscale_kernel<<<1, 256, 0, stream>>>(Wl, bl, scale, wlsc);
  pack_w_kernel<<<dim3(8, 32, 15), 256, 0, stream>>>(Wq, Wk, Wv, Ws, Wp);
  pack_b_kernel<<<15, 256, 0, stream>>>(bq, bk, bv, bs, bp);
  pack_wqe_kernel<<<15, 256, 0, stream>>>(Wq, We, bq, Wqe, bqe);

  int agg_blocks = (N + 7) / 8;

  // conv1
  gemm1_kernel<<<(N + 63) / 64, 256, 0, stream>>>(hx, Wq1, Wk1, Wv1, Ws1,
                                                  bq1, bk1, bv1, bs1, qkvh, slh, N);
  qwe1_kernel<<<(N + 3) / 4, 256, 0, stream>>>(qkvh, We1, qwe, N);
  agg_kernel<<<agg_blocks, 256, 0, stream>>>(qkvh, slh, qwe, ea_csr, src_csr, We1,
                                             Wqe, bqe, row_ptr,
                                             hh, hh, h2b, qwe, wlsc, out, 0, 0, N, E);

  // 15 residual blocks
  for (int l = 0; l < 15; l++){
    gemm_mfma_kernel<<<dim3(Mpad / 128, 8), 256, 0, stream>>>(
        h2b, Wp + (size_t)l * 262144, bp + (size_t)l * 1024, qkvh, slh, N);
    int last = (l == 14);
    const float* wqe_n = (l < 14) ? (Wqe + (size_t)(l + 1) * 1024) : nullptr;
    const float* bqe_n = (l < 14) ? (bqe + (size_t)(l + 1) * 4) : nullptr;
    agg_kernel<<<agg_blocks, 256, 0, stream>>>(qkvh, slh, qwe, ea_csr, src_csr,
                                               We + (size_t)l * 1024,
                                               wqe_n, bqe_n, row_ptr,
                                               hh, hh, h2b, qwe, wlsc, out, 1, last, N, E);
  }
}

// Round 13
// 1075.042 us; speedup vs baseline: 1.0837x; 1.0748x over previous
//
#include <hip/hip_runtime.h>
#include <math.h>

typedef short bf16x8 __attribute__((ext_vector_type(8)));
typedef float f32x4 __attribute__((ext_vector_type(4)));
typedef _Float16 h16x8 __attribute__((ext_vector_type(8)));
typedef _Float16 h16x4 __attribute__((ext_vector_type(4)));
typedef _Float16 h16x2 __attribute__((ext_vector_type(2)));

static __device__ __forceinline__ float wred_sum(float v){
  #pragma unroll
  for (int o = 32; o > 0; o >>= 1) v += __shfl_xor(v, o, 64);
  return v;
}

static __device__ __forceinline__ unsigned short f2bf(float x){
  union { float f; unsigned int u; } c; c.f = x;
  unsigned int u = c.u;
  return (unsigned short)((u + 0x7FFFu + ((u >> 16) & 1u)) >> 16);
}

// ---------------- prep ----------------
__global__ void prep_kernel(const float* __restrict__ x, const float* __restrict__ ea_in,
                            float* __restrict__ hx, float* __restrict__ ea,
                            int nx, int ne){
  int i = blockIdx.x * 256 + threadIdx.x;
  if (i < nx) hx[i] = logf(x[i] + 1.f);
  if (i < ne) ea[i] = logf(ea_in[i] + 1.f);
}

// ---------------- CSR build ----------------
__global__ void zero_kernel(int* __restrict__ c, int n){
  int i = blockIdx.x * 256 + threadIdx.x;
  if (i < n) c[i] = 0;
}

__global__ void hist_kernel(const int* __restrict__ dst, int* __restrict__ counts, int E){
  int i = blockIdx.x * 256 + threadIdx.x;
  if (i < E) atomicAdd(&counts[dst[i]], 1);
}

// wave-shfl hierarchical scan
__global__ __launch_bounds__(1024) void scan_kernel(const int* __restrict__ counts,
                                                    int* __restrict__ row_ptr,
                                                    int* __restrict__ cursor, int N){
  __shared__ int woff[16];
  __shared__ int carry_s;
  int t = threadIdx.x, lane = t & 63, wid = t >> 6;
  if (t == 0) carry_s = 0;
  __syncthreads();
  for (int base = 0; base < N; base += 1024){
    int i = base + t;
    int v = (i < N) ? counts[i] : 0;
    int incl = v;
    #pragma unroll
    for (int o = 1; o < 64; o <<= 1){
      int tmp = __shfl_up(incl, o, 64);
      if (lane >= o) incl += tmp;
    }
    if (lane == 63) woff[wid] = incl;
    __syncthreads();
    if (t < 16){
      int w = woff[t];
      int inc2 = w;
      #pragma unroll
      for (int o = 1; o < 16; o <<= 1){
        int tmp = __shfl_up(inc2, o, 16);
        if (t >= o) inc2 += tmp;
      }
      woff[t] = inc2 - w;
    }
    __syncthreads();
    int ex = carry_s + woff[wid] + incl - v;
    if (i < N){ row_ptr[i] = ex; cursor[i] = ex; }
    __syncthreads();
    if (t == 1023) carry_s = ex + v;
    __syncthreads();
  }
  if (t == 0) row_ptr[N] = carry_s;
}

__global__ void scatter_kernel(const int* __restrict__ src, const int* __restrict__ dst,
                               const float* __restrict__ ea,
                               int* __restrict__ cursor,
                               int* __restrict__ src_csr, float* __restrict__ ea_csr, int E){
  int i = blockIdx.x * 256 + threadIdx.x;
  if (i < E){
    int p = atomicAdd(&cursor[dst[i]], 1);
    src_csr[p] = src[i];
    *(float4*)&ea_csr[(size_t)p * 4] = *(const float4*)&ea[(size_t)i * 4];
  }
}

// ---------------- head helper ----------------
__global__ void wlscale_kernel(const float* __restrict__ Wl, const float* __restrict__ bl,
                               const float* __restrict__ scale, float* __restrict__ wlsc){
  int c = threadIdx.x;
  float s = 0.f;
  #pragma unroll
  for (int j = 0; j < 8; j++) s += Wl[c * 8 + j] * scale[j];
  wlsc[c] = s;
  if (c == 0){
    float b = 0.f;
    #pragma unroll
    for (int j = 0; j < 8; j++) b += bl[j] * scale[j];
    wlsc[256] = b;
  }
}

// ---------------- weight pack (bf16 W^T for MFMA) ----------------
__global__ __launch_bounds__(256) void pack_w_kernel(
    const float* __restrict__ Wq, const float* __restrict__ Wk,
    const float* __restrict__ Wv, const float* __restrict__ Ws,
    unsigned short* __restrict__ Wp)
{
  __shared__ float t[32][33];
  int l   = blockIdx.z;
  int k0  = blockIdx.x * 32;
  int n0g = blockIdx.y * 32;
  int w   = n0g >> 8;
  int n0  = n0g & 255;
  const float* W = ((w == 0) ? Wq : (w == 1) ? Wk : (w == 2) ? Wv : Ws) + (size_t)l * 65536;
  int rr = threadIdx.x >> 3;
  int cc = (threadIdx.x & 7) * 4;
  float4 vv = *(const float4*)&W[(size_t)(k0 + rr) * 256 + n0 + cc];
  t[rr][cc + 0] = vv.x; t[rr][cc + 1] = vv.y; t[rr][cc + 2] = vv.z; t[rr][cc + 3] = vv.w;
  __syncthreads();
  ushort4 o;
  o.x = f2bf(t[cc + 0][rr]);
  o.y = f2bf(t[cc + 1][rr]);
  o.z = f2bf(t[cc + 2][rr]);
  o.w = f2bf(t[cc + 3][rr]);
  *(ushort4*)&Wp[(size_t)l * 262144 + (size_t)(n0g + rr) * 256 + k0 + cc] = o;
}

__global__ void pack_b_kernel(const float* __restrict__ bq, const float* __restrict__ bk,
                              const float* __restrict__ bv, const float* __restrict__ bs,
                              float* __restrict__ bp){
  int i = blockIdx.x * 256 + threadIdx.x;
  if (i < 15 * 256){
    int l = i >> 8, n = i & 255;
    bp[l * 1024 + 0   + n] = bq[i];
    bp[l * 1024 + 256 + n] = bk[i];
    bp[l * 1024 + 512 + n] = bv[i];
    bp[l * 1024 + 768 + n] = bs[i];
  }
}

// ---------------- pack Wqe ----------------
__global__ __launch_bounds__(256) void pack_wqe_kernel(
    const float* __restrict__ Wq, const float* __restrict__ We,
    const float* __restrict__ bq, float* __restrict__ Wqe, float* __restrict__ bqe)
{
  __shared__ float We_s[1024];
  int l = blockIdx.x;
  for (int i = threadIdx.x; i < 1024; i += 256) We_s[i] = We[(size_t)l * 1024 + i];
  __syncthreads();
  int k = threadIdx.x;
  const float* wrow = Wq + (size_t)l * 65536 + (size_t)k * 256;
  float s0 = 0.f, s1 = 0.f, s2 = 0.f, s3 = 0.f;
  for (int c = 0; c < 256; c++){
    float wv = wrow[c];
    s0 += wv * We_s[c];
    s1 += wv * We_s[256 + c];
    s2 += wv * We_s[512 + c];
    s3 += wv * We_s[768 + c];
  }
  float4 o; o.x = s0; o.y = s1; o.z = s2; o.w = s3;
  *(float4*)&Wqe[((size_t)l * 256 + k) * 4] = o;
  if (k < 4){
    float b = 0.f;
    for (int c = 0; c < 256; c++) b += bq[l * 256 + c] * We_s[k * 256 + c];
    bqe[l * 4 + k] = b;
  }
}

// ---------------- qwe for conv1 ----------------
__global__ __launch_bounds__(256) void qwe1_kernel(const _Float16* __restrict__ qkvh,
                                                   const float* __restrict__ We1,
                                                   float* __restrict__ qwe, int N){
  __shared__ float We_s[1024];
  for (int i = threadIdx.x; i < 1024; i += 256) We_s[i] = We1[i];
  __syncthreads();
  int wid = threadIdx.x >> 6, lane = threadIdx.x & 63;
  int n = blockIdx.x * 4 + wid;
  if (n >= N) return;
  int c0 = lane * 4;
  h16x4 qr = *(const h16x4*)&qkvh[(size_t)n * 768 + c0];
  float q0 = (float)qr[0], q1 = (float)qr[1], q2 = (float)qr[2], q3 = (float)qr[3];
  float4 o;
  #pragma unroll
  for (int j = 0; j < 4; j++){
    float s = q0 * We_s[j * 256 + c0] + q1 * We_s[j * 256 + c0 + 1]
            + q2 * We_s[j * 256 + c0 + 2] + q3 * We_s[j * 256 + c0 + 3];
    s = wred_sum(s);
    if (j == 0) o.x = s; else if (j == 1) o.y = s; else if (j == 2) o.z = s; else o.w = s;
  }
  if (lane == 0) *(float4*)&qwe[(size_t)n * 4] = o;
}

// ---------------- conv1 GEMMs ----------------
__global__ __launch_bounds__(256) void gemm1_kernel(
    const float* __restrict__ A,
    const float* __restrict__ W0, const float* __restrict__ W1,
    const float* __restrict__ W2, const float* __restrict__ W3,
    const float* __restrict__ B0, const float* __restrict__ B1,
    const float* __restrict__ B2, const float* __restrict__ B3,
    _Float16* __restrict__ qkvh, _Float16* __restrict__ slh, int N)
{
  __shared__ float As[64][16];
  int nb = blockIdx.x * 64;
  {
    int row = nb + (threadIdx.x >> 2);
    int qq = (threadIdx.x & 3) * 4;
    float4 a = make_float4(0.f, 0.f, 0.f, 0.f);
    if (row < N) a = *(const float4*)&A[row * 16 + qq];
    *(float4*)&As[threadIdx.x >> 2][qq] = a;
  }
  __syncthreads();
  int col = threadIdx.x;
  #pragma unroll
  for (int w = 0; w < 4; w++){
    const float* W  = (w == 0) ? W0 : (w == 1) ? W1 : (w == 2) ? W2 : W3;
    const float* Bi = (w == 0) ? B0 : (w == 1) ? B1 : (w == 2) ? B2 : B3;
    float wr[16];
    #pragma unroll
    for (int kk = 0; kk < 16; kk++) wr[kk] = W[kk * 256 + col];
    float bias = Bi[col];
    for (int r = 0; r < 64; r++){
      int row = nb + r;
      if (row >= N) break;
      float acc = bias;
      #pragma unroll
      for (int kk = 0; kk < 16; kk++) acc += As[r][kk] * wr[kk];
      if (w < 3) qkvh[(size_t)row * 768 + w * 256 + col] = (_Float16)acc;
      else       slh[(size_t)row * 256 + col] = (_Float16)acc;
    }
  }
}

// ---------------- main MFMA GEMM (XCD-swizzled, LDS-staged epilogue) ----------------
__global__ __launch_bounds__(256, 3) void gemm_mfma_kernel(
    const unsigned short* __restrict__ A,
    const unsigned short* __restrict__ Wp,
    const float* __restrict__ bp,
    _Float16* __restrict__ qkvh,
    _Float16* __restrict__ slh,
    int M)
{
  __shared__ unsigned short lds[2 * 128 * 64];
  unsigned short* ldsA = lds;
  unsigned short* ldsB = lds + 128 * 64;
  const int tid  = threadIdx.x;
  const int wave = tid >> 6, lane = tid & 63;
  const int wm = wave >> 1, wn = wave & 1;
  const int rt  = (int)gridDim.x;
  const int lin = (int)blockIdx.x + rt * (int)blockIdx.y;
  const int gt  = (lin & 7) * rt + (lin >> 3);
  const int m0 = (gt >> 3) * 128;
  const int n0 = (gt & 7) * 128;

  f32x4 acc[4][4] = {};

  const int srow  = lane >> 3;
  const int sc16  = lane & 7;
  const int skgrp = sc16 ^ (srow & 7);

  for (int k0 = 0; k0 < 256; k0 += 64){
    #pragma unroll
    for (int it = 0; it < 4; ++it){
      int lrow = wave * 32 + it * 8;
      const unsigned short* gA = A + (size_t)(m0 + lrow + srow) * 256 + k0 + skgrp * 8;
      __builtin_amdgcn_global_load_lds((const __attribute__((address_space(1))) unsigned int*)gA,
          (__attribute__((address_space(3))) unsigned int*)(ldsA + lrow * 64), 16, 0, 0);
      const unsigned short* gB = Wp + (size_t)(n0 + lrow + srow) * 256 + k0 + skgrp * 8;
      __builtin_amdgcn_global_load_lds((const __attribute__((address_space(1))) unsigned int*)gB,
          (__attribute__((address_space(3))) unsigned int*)(ldsB + lrow * 64), 16, 0, 0);
    }
    __syncthreads();

    bf16x8 af[4][2], bfr[4][2];
    #pragma unroll
    for (int mb = 0; mb < 4; ++mb){
      int r = wm * 64 + mb * 16 + (lane & 15);
      #pragma unroll
      for (int ks = 0; ks < 2; ++ks){
        int kg = ks * 4 + (lane >> 4);
        af[mb][ks] = *(const bf16x8*)&ldsA[r * 64 + ((kg ^ (r & 7)) * 8)];
      }
    }
    #pragma unroll
    for (int nb = 0; nb < 4; ++nb){
      int r = wn * 64 + nb * 16 + (lane & 15);
      #pragma unroll
      for (int ks = 0; ks < 2; ++ks){
        int kg = ks * 4 + (lane >> 4);
        bfr[nb][ks] = *(const bf16x8*)&ldsB[r * 64 + ((kg ^ (r & 7)) * 8)];
      }
    }
    #pragma unroll
    for (int mb = 0; mb < 4; ++mb){
      #pragma unroll
      for (int nb = 0; nb < 4; ++nb){
        acc[mb][nb] = __builtin_amdgcn_mfma_f32_16x16x32_bf16(af[mb][0], bfr[nb][0], acc[mb][nb], 0, 0, 0);
        acc[mb][nb] = __builtin_amdgcn_mfma_f32_16x16x32_bf16(af[mb][1], bfr[nb][1], acc[mb][nb], 0, 0, 0);
      }
    }
    __syncthreads();
  }

  _Float16* lt = (_Float16*)lds;   // [128][128], col ^ ((row>>2)&3)<<4
  #pragma unroll
  for (int nb = 0; nb < 4; ++nb){
    int col = wn * 64 + nb * 16 + (lane & 15);
    float bias = bp[n0 + col];
    #pragma unroll
    for (int mb = 0; mb < 4; ++mb){
      #pragma unroll
      for (int r4 = 0; r4 < 4; ++r4){
        int row = wm * 64 + mb * 16 + (lane >> 4) * 4 + r4;
        lt[row * 128 + (col ^ (((row >> 2) & 3) << 4))] = (_Float16)(acc[mb][nb][r4] + bias);
      }
    }
  }
  __syncthreads();
  int tr = tid >> 4;
  int tc = (tid & 15) * 8;
  if (n0 < 768){
    #pragma unroll
    for (int it = 0; it < 8; ++it){
      int row = tr + it * 16;
      int grow = m0 + row;
      if (grow < M){
        h16x8 v8 = *(const h16x8*)&lt[row * 128 + (tc ^ (((row >> 2) & 3) << 4))];
        *(h16x8*)&qkvh[(size_t)grow * 768 + n0 + tc] = v8;
      }
    }
  } else {
    #pragma unroll
    for (int it = 0; it < 8; ++it){
      int row = tr + it * 16;
      int grow = m0 + row;
      if (grow < M){
        h16x8 v8 = *(const h16x8*)&lt[row * 128 + (tc ^ (((row >> 2) & 3) << 4))];
        *(h16x8*)&slh[(size_t)grow * 256 + (n0 - 768) + tc] = v8;
      }
    }
  }
}

// ---------------- fused attention aggregation (+head on last layer) ----------------
// R8 structure (empirically best): one wave per node, 8 edge-slots x 8 lanes x 32ch
// for the q.k dot, inline channel-parallel v/ea loads, low VGPR. h in f16.
__global__ __launch_bounds__(256) void agg_kernel(
    const _Float16* __restrict__ qkvh,
    const _Float16* __restrict__ slh,
    const float* __restrict__ qwe,
    const float* __restrict__ ea_csr,
    const int* __restrict__ src_csr,
    const float* __restrict__ We,
    const float* __restrict__ Wqe_next,
    const float* __restrict__ bqe_next,
    const int* __restrict__ row_ptr,
    const _Float16* __restrict__ h_in, _Float16* __restrict__ h_out,
    unsigned short* __restrict__ h2b, float* __restrict__ qwe_out,
    const float* __restrict__ wlsc, float* __restrict__ out,
    int RESID, int LAST, int N)
{
  int wid = threadIdx.x >> 6, lane = threadIdx.x & 63;
  int n = blockIdx.x * 4 + wid;
  if (n >= N) return;
  int c0 = lane * 4;
  int glane = lane >> 3;          // edge slot 0..7
  int slane = lane & 7;           // channel group (32 ch each)
  union hu { h16x8 v; h16x2 p[4]; };

  int e0 = row_ptr[n], e1 = row_ptr[n + 1];
  float4 qwe4 = *(const float4*)&qwe[(size_t)n * 4];
  h16x4 slv4 = *(const h16x4*)&slh[(size_t)n * 256 + c0];
  h16x4 hpv = {};
  if (RESID) hpv = *(const h16x4*)&h_in[(size_t)n * 256 + c0];
  const _Float16* qrow = qkvh + (size_t)n * 768 + slane * 32;
  hu qf[4];
  #pragma unroll
  for (int u = 0; u < 4; ++u) qf[u].v = *(const h16x8*)(qrow + u * 8);

  float m = -INFINITY, ssum = 0.f;
  float a0 = 0.f, a1 = 0.f, a2 = 0.f, a3 = 0.f;
  float ec0 = 0.f, ec1 = 0.f, ec2 = 0.f, ec3 = 0.f;

  for (int base = e0; base < e1; base += 8){
    int cnt = min(8, e1 - base);
    int eg = base + ((glane < cnt) ? glane : (cnt - 1));
    int sg = src_csr[eg];
    float4 eag = *(const float4*)&ea_csr[(size_t)eg * 4];
    const _Float16* krow = qkvh + (size_t)sg * 768 + 256 + slane * 32;
    float dot = 0.f;
    #pragma unroll
    for (int u = 0; u < 4; ++u){
      hu kf;
      kf.v = *(const h16x8*)(krow + u * 8);
      #pragma unroll
      for (int pp = 0; pp < 4; ++pp){
#if __has_builtin(__builtin_amdgcn_fdot2)
        dot = __builtin_amdgcn_fdot2(qf[u].p[pp], kf.p[pp], dot, false);
#else
        dot += (float)qf[u].p[pp][0] * (float)kf.p[pp][0] + (float)qf[u].p[pp][1] * (float)kf.p[pp][1];
#endif
      }
    }
    #pragma unroll
    for (int o = 1; o < 8; o <<= 1) dot += __shfl_xor(dot, o, 64);
    float alpha_g = (dot + qwe4.x * eag.x + qwe4.y * eag.y + qwe4.z * eag.z + qwe4.w * eag.w) * 0.0625f;
    float aj[8];
    #pragma unroll
    for (int j = 0; j < 8; ++j){
      aj[j] = __shfl(alpha_g, j << 3, 64);
      if (j >= cnt) aj[j] = -INFINITY;
    }
    float mc = fmaxf(fmaxf(fmaxf(aj[0], aj[1]), fmaxf(aj[2], aj[3])),
                     fmaxf(fmaxf(aj[4], aj[5]), fmaxf(aj[6], aj[7])));
    float mn = fmaxf(m, mc);
    float corr = expf(m - mn);
    float wj[8];
    float wtot = 0.f;
    #pragma unroll
    for (int j = 0; j < 8; ++j){
      wj[j] = (j < cnt) ? expf(aj[j] - mn) : 0.f;
      wtot += wj[j];
    }
    ssum = ssum * corr + wtot;
    a0 *= corr; a1 *= corr; a2 *= corr; a3 *= corr;
    ec0 *= corr; ec1 *= corr; ec2 *= corr; ec3 *= corr;
    m = mn;
    int sg_bc = sg;
    #pragma unroll
    for (int j = 0; j < 8; ++j){
      if (j < cnt){
        int sj = __shfl(sg_bc, j << 3, 64);
        h16x4 vr = *(const h16x4*)&qkvh[(size_t)sj * 768 + 512 + c0];
        float4 er = *(const float4*)&ea_csr[(size_t)(base + j) * 4];
        a0 += wj[j] * (float)vr[0];
        a1 += wj[j] * (float)vr[1];
        a2 += wj[j] * (float)vr[2];
        a3 += wj[j] * (float)vr[3];
        ec0 += wj[j] * er.x;
        ec1 += wj[j] * er.y;
        ec2 += wj[j] * er.z;
        ec3 += wj[j] * er.w;
      }
    }
  }

  float inv = 1.f / (ssum + 1e-16f);
  float4 W0 = *(const float4*)&We[0 * 256 + c0];
  float4 W1 = *(const float4*)&We[1 * 256 + c0];
  float4 W2 = *(const float4*)&We[2 * 256 + c0];
  float4 W3 = *(const float4*)&We[3 * 256 + c0];
  float emb0 = ec0 * W0.x + ec1 * W1.x + ec2 * W2.x + ec3 * W3.x;
  float emb1 = ec0 * W0.y + ec1 * W1.y + ec2 * W2.y + ec3 * W3.y;
  float emb2 = ec0 * W0.z + ec1 * W1.z + ec2 * W2.z + ec3 * W3.z;
  float emb3 = ec0 * W0.w + ec1 * W1.w + ec2 * W2.w + ec3 * W3.w;
  float y0 = (a0 + emb0) * inv + (float)slv4[0];
  float y1 = (a1 + emb1) * inv + (float)slv4[1];
  float y2 = (a2 + emb2) * inv + (float)slv4[2];
  float y3 = (a3 + emb3) * inv + (float)slv4[3];
  float o0 = y0, o1 = y1, o2 = y2, o3 = y3;
  if (RESID){
    o0 += (float)hpv[0]; o1 += (float)hpv[1]; o2 += (float)hpv[2]; o3 += (float)hpv[3];
  }
  if (LAST){
    float4 wv = *(const float4*)&wlsc[c0];
    float pp = o0 * wv.x + o1 * wv.y + o2 * wv.z + o3 * wv.w;
    pp = wred_sum(pp);
    if (lane == 0) out[n] = pp * (1.f / sqrtf(15.f)) + wlsc[256];
    return;
  }
  h16x4 ho;
  ho[0] = (_Float16)o0; ho[1] = (_Float16)o1; ho[2] = (_Float16)o2; ho[3] = (_Float16)o3;
  *(h16x4*)&h_out[(size_t)n * 256 + c0] = ho;
  float mean = wred_sum(o0 + o1 + o2 + o3) * (1.f / 256.f);
  float d0 = o0 - mean, d1 = o1 - mean, d2 = o2 - mean, d3 = o3 - mean;
  float var = wred_sum(d0 * d0 + d1 * d1 + d2 * d2 + d3 * d3) * (1.f / 255.f);
  float invstd = 1.f / sqrtf(var);
  float t0 = fmaxf(o0 * invstd, 0.f);
  float t1 = fmaxf(o1 * invstd, 0.f);
  float t2 = fmaxf(o2 * invstd, 0.f);
  float t3 = fmaxf(o3 * invstd, 0.f);
  ushort4 hb;
  hb.x = f2bf(t0); hb.y = f2bf(t1); hb.z = f2bf(t2); hb.w = f2bf(t3);
  *(ushort4*)&h2b[(size_t)n * 256 + c0] = hb;
  if (Wqe_next){
    float4 g0 = *(const float4*)&Wqe_next[(c0 + 0) * 4];
    float4 g1 = *(const float4*)&Wqe_next[(c0 + 1) * 4];
    float4 g2 = *(const float4*)&Wqe_next[(c0 + 2) * 4];
    float4 g3 = *(const float4*)&Wqe_next[(c0 + 3) * 4];
    float s0 = t0 * g0.x + t1 * g1.x + t2 * g2.x + t3 * g3.x;
    float s1 = t0 * g0.y + t1 * g1.y + t2 * g2.y + t3 * g3.y;
    float s2 = t0 * g0.z + t1 * g1.z + t2 * g2.z + t3 * g3.z;
    float s3 = t0 * g0.w + t1 * g1.w + t2 * g2.w + t3 * g3.w;
    s0 = wred_sum(s0); s1 = wred_sum(s1); s2 = wred_sum(s2); s3 = wred_sum(s3);
    if (lane == 0){
      float4 bq4 = *(const float4*)bqe_next;
      float4 o; o.x = s0 + bq4.x; o.y = s1 + bq4.y; o.z = s2 + bq4.z; o.w = s3 + bq4.w;
      *(float4*)&qwe_out[(size_t)n * 4] = o;
    }
  }
}

// ---------------- launch ----------------
extern "C" void kernel_launch(void* const* d_in, const int* in_sizes, int n_in,
                              void* d_out, int out_size, void* d_ws, size_t ws_size,
                              hipStream_t stream)
{
  const float* x     = (const float*)d_in[0];
  const int*   eidx  = (const int*)d_in[1];
  const float* Wq1 = (const float*)d_in[3];  const float* bq1 = (const float*)d_in[4];
  const float* Wk1 = (const float*)d_in[5];  const float* bk1 = (const float*)d_in[6];
  const float* Wv1 = (const float*)d_in[7];  const float* bv1 = (const float*)d_in[8];
  const float* We1 = (const float*)d_in[9];
  const float* Ws1 = (const float*)d_in[10]; const float* bs1 = (const float*)d_in[11];
  const float* Wq = (const float*)d_in[12];  const float* bq = (const float*)d_in[13];
  const float* Wk = (const float*)d_in[14];  const float* bk = (const float*)d_in[15];
  const float* Wv = (const float*)d_in[16];  const float* bv = (const float*)d_in[17];
  const float* We = (const float*)d_in[18];
  const float* Ws = (const float*)d_in[19];  const float* bs = (const float*)d_in[20];
  const float* Wl = (const float*)d_in[21];  const float* bl = (const float*)d_in[22];
  const float* scale = (const float*)d_in[23];
  (void)n_in; (void)ws_size;

  int N = in_sizes[0] / 16;
  int E = in_sizes[2] / 4;
  int Mpad = (N + 127) & ~127;
  float* out = (float*)d_out;
  (void)out_size;

  char* p = (char*)d_ws;
  auto alloc = [&](size_t bytes) -> char* {
    char* r = p; p += (bytes + 255) & ~(size_t)255; return r;
  };
  float* hx   = (float*)alloc((size_t)N * 16 * 4);
  float* ea   = (float*)alloc((size_t)E * 4 * 4);
  _Float16* hh = (_Float16*)alloc((size_t)N * 256 * 2);
  unsigned short* h2b = (unsigned short*)alloc((size_t)Mpad * 256 * 2);
  _Float16* qkvh = (_Float16*)alloc((size_t)N * 768 * 2);
  _Float16* slh  = (_Float16*)alloc((size_t)N * 256 * 2);
  float* qwe  = (float*)alloc((size_t)N * 4 * 4);
  float* ea_csr = (float*)alloc((size_t)E * 4 * 4);
  int* src_csr  = (int*)alloc((size_t)E * 4);
  unsigned short* Wp  = (unsigned short*)alloc((size_t)15 * 1024 * 256 * 2);
  float* bp   = (float*)alloc((size_t)15 * 1024 * 4);
  float* Wqe  = (float*)alloc((size_t)15 * 256 * 4 * 4);
  float* bqe  = (float*)alloc((size_t)15 * 4 * 4);
  float* wlsc = (float*)alloc(257 * 4);
  int* counts  = (int*)alloc((size_t)N * 4);
  int* cursor  = (int*)alloc((size_t)N * 4);
  int* row_ptr = (int*)alloc(((size_t)N + 1) * 4);

  const int* srcp = eidx;
  const int* dstp = eidx + E;

  int nx = N * 16, ne = E * 4;
  int big = nx > ne ? nx : ne;

  zero_kernel<<<(N + 255) / 256, 256, 0, stream>>>(counts, N);
  prep_kernel<<<(big + 255) / 256, 256, 0, stream>>>(x, (const float*)d_in[2], hx, ea, nx, ne);
  hist_kernel<<<(E + 255) / 256, 256, 0, stream>>>(dstp, counts, E);
  scan_kernel<<<1, 1024, 0, stream>>>(counts, row_ptr, cursor, N);
  scatter_kernel<<<(E + 255) / 256, 256, 0, stream>>>(srcp, dstp, ea, cursor,
                                                      src_csr, ea_csr, E);
  wlscale_kernel<<<1, 256, 0, stream>>>(Wl, bl, scale, wlsc);
  pack_w_kernel<<<dim3(8, 32, 15), 256, 0, stream>>>(Wq, Wk, Wv, Ws, Wp);
  pack_b_kernel<<<15, 256, 0, stream>>>(bq, bk, bv, bs, bp);
  pack_wqe_kernel<<<15, 256, 0, stream>>>(Wq, We, bq, Wqe, bqe);

  int agg_blocks = (N + 3) / 4;

  // conv1
  gemm1_kernel<<<(N + 63) / 64, 256, 0, stream>>>(hx, Wq1, Wk1, Wv1, Ws1,
                                                  bq1, bk1, bv1, bs1, qkvh, slh, N);
  qwe1_kernel<<<(N + 3) / 4, 256, 0, stream>>>(qkvh, We1, qwe, N);
  agg_kernel<<<agg_blocks, 256, 0, stream>>>(qkvh, slh, qwe, ea_csr, src_csr, We1,
                                             Wqe, bqe, row_ptr,
                                             hh, hh, h2b, qwe, wlsc, out, 0, 0, N);

  // 15 residual blocks
  for (int l = 0; l < 15; l++){
    gemm_mfma_kernel<<<dim3(Mpad / 128, 8), 256, 0, stream>>>(
        h2b, Wp + (size_t)l * 262144, bp + (size_t)l * 1024, qkvh, slh, N);
    int last = (l == 14);
    const float* wqe_n = (l < 14) ? (Wqe + (size_t)(l + 1) * 1024) : nullptr;
    const float* bqe_n = (l < 14) ? (bqe + (size_t)(l + 1) * 4) : nullptr;
    agg_kernel<<<agg_blocks, 256, 0, stream>>>(qkvh, slh, qwe, ea_csr, src_csr,
                                               We + (size_t)l * 1024,
                                               wqe_n, bqe_n, row_ptr,
                                               hh, hh, h2b, qwe, wlsc, out, 1, last, N);
  }
}

// Round 14
// 1040.582 us; speedup vs baseline: 1.1196x; 1.0331x over previous
//
#include <hip/hip_runtime.h>
#include <math.h>

typedef short bf16x8 __attribute__((ext_vector_type(8)));
typedef float f32x4 __attribute__((ext_vector_type(4)));
typedef _Float16 h16x8 __attribute__((ext_vector_type(8)));
typedef _Float16 h16x4 __attribute__((ext_vector_type(4)));
typedef _Float16 h16x2 __attribute__((ext_vector_type(2)));

static __device__ __forceinline__ float wred_sum(float v){
  #pragma unroll
  for (int o = 32; o > 0; o >>= 1) v += __shfl_xor(v, o, 64);
  return v;
}

static __device__ __forceinline__ unsigned short f2bf(float x){
  union { float f; unsigned int u; } c; c.f = x;
  unsigned int u = c.u;
  return (unsigned short)((u + 0x7FFFu + ((u >> 16) & 1u)) >> 16);
}

// ---------------- prep ----------------
__global__ void prep_kernel(const float* __restrict__ x, const float* __restrict__ ea_in,
                            float* __restrict__ hx, float* __restrict__ ea,
                            int nx, int ne){
  int i = blockIdx.x * 256 + threadIdx.x;
  if (i < nx) hx[i] = logf(x[i] + 1.f);
  if (i < ne) ea[i] = logf(ea_in[i] + 1.f);
}

// ---------------- CSR build ----------------
__global__ void zero_kernel(int* __restrict__ c, int n){
  int i = blockIdx.x * 256 + threadIdx.x;
  if (i < n) c[i] = 0;
}

__global__ void hist_kernel(const int* __restrict__ dst, int* __restrict__ counts, int E){
  int i = blockIdx.x * 256 + threadIdx.x;
  if (i < E) atomicAdd(&counts[dst[i]], 1);
}

// wave-shfl hierarchical scan
__global__ __launch_bounds__(1024) void scan_kernel(const int* __restrict__ counts,
                                                    int* __restrict__ row_ptr,
                                                    int* __restrict__ cursor, int N){
  __shared__ int woff[16];
  __shared__ int carry_s;
  int t = threadIdx.x, lane = t & 63, wid = t >> 6;
  if (t == 0) carry_s = 0;
  __syncthreads();
  for (int base = 0; base < N; base += 1024){
    int i = base + t;
    int v = (i < N) ? counts[i] : 0;
    int incl = v;
    #pragma unroll
    for (int o = 1; o < 64; o <<= 1){
      int tmp = __shfl_up(incl, o, 64);
      if (lane >= o) incl += tmp;
    }
    if (lane == 63) woff[wid] = incl;
    __syncthreads();
    if (t < 16){
      int w = woff[t];
      int inc2 = w;
      #pragma unroll
      for (int o = 1; o < 16; o <<= 1){
        int tmp = __shfl_up(inc2, o, 16);
        if (t >= o) inc2 += tmp;
      }
      woff[t] = inc2 - w;
    }
    __syncthreads();
    int ex = carry_s + woff[wid] + incl - v;
    if (i < N){ row_ptr[i] = ex; cursor[i] = ex; }
    __syncthreads();
    if (t == 1023) carry_s = ex + v;
    __syncthreads();
  }
  if (t == 0) row_ptr[N] = carry_s;
}

__global__ void scatter_kernel(const int* __restrict__ src, const int* __restrict__ dst,
                               const float* __restrict__ ea,
                               int* __restrict__ cursor,
                               int* __restrict__ src_csr, float* __restrict__ ea_csr, int E){
  int i = blockIdx.x * 256 + threadIdx.x;
  if (i < E){
    int p = atomicAdd(&cursor[dst[i]], 1);
    src_csr[p] = src[i];
    *(float4*)&ea_csr[(size_t)p * 4] = *(const float4*)&ea[(size_t)i * 4];
  }
}

// ---------------- head helper ----------------
__global__ void wlscale_kernel(const float* __restrict__ Wl, const float* __restrict__ bl,
                               const float* __restrict__ scale, float* __restrict__ wlsc){
  int c = threadIdx.x;
  float s = 0.f;
  #pragma unroll
  for (int j = 0; j < 8; j++) s += Wl[c * 8 + j] * scale[j];
  wlsc[c] = s;
  if (c == 0){
    float b = 0.f;
    #pragma unroll
    for (int j = 0; j < 8; j++) b += bl[j] * scale[j];
    wlsc[256] = b;
  }
}

// ---------------- weight pack (bf16 W^T for MFMA) ----------------
__global__ __launch_bounds__(256) void pack_w_kernel(
    const float* __restrict__ Wq, const float* __restrict__ Wk,
    const float* __restrict__ Wv, const float* __restrict__ Ws,
    unsigned short* __restrict__ Wp)
{
  __shared__ float t[32][33];
  int l   = blockIdx.z;
  int k0  = blockIdx.x * 32;
  int n0g = blockIdx.y * 32;
  int w   = n0g >> 8;
  int n0  = n0g & 255;
  const float* W = ((w == 0) ? Wq : (w == 1) ? Wk : (w == 2) ? Wv : Ws) + (size_t)l * 65536;
  int rr = threadIdx.x >> 3;
  int cc = (threadIdx.x & 7) * 4;
  float4 vv = *(const float4*)&W[(size_t)(k0 + rr) * 256 + n0 + cc];
  t[rr][cc + 0] = vv.x; t[rr][cc + 1] = vv.y; t[rr][cc + 2] = vv.z; t[rr][cc + 3] = vv.w;
  __syncthreads();
  ushort4 o;
  o.x = f2bf(t[cc + 0][rr]);
  o.y = f2bf(t[cc + 1][rr]);
  o.z = f2bf(t[cc + 2][rr]);
  o.w = f2bf(t[cc + 3][rr]);
  *(ushort4*)&Wp[(size_t)l * 262144 + (size_t)(n0g + rr) * 256 + k0 + cc] = o;
}

__global__ void pack_b_kernel(const float* __restrict__ bq, const float* __restrict__ bk,
                              const float* __restrict__ bv, const float* __restrict__ bs,
                              float* __restrict__ bp){
  int i = blockIdx.x * 256 + threadIdx.x;
  if (i < 15 * 256){
    int l = i >> 8, n = i & 255;
    bp[l * 1024 + 0   + n] = bq[i];
    bp[l * 1024 + 256 + n] = bk[i];
    bp[l * 1024 + 512 + n] = bv[i];
    bp[l * 1024 + 768 + n] = bs[i];
  }
}

// ---------------- pack Wqe ----------------
__global__ __launch_bounds__(256) void pack_wqe_kernel(
    const float* __restrict__ Wq, const float* __restrict__ We,
    const float* __restrict__ bq, float* __restrict__ Wqe, float* __restrict__ bqe)
{
  __shared__ float We_s[1024];
  int l = blockIdx.x;
  for (int i = threadIdx.x; i < 1024; i += 256) We_s[i] = We[(size_t)l * 1024 + i];
  __syncthreads();
  int k = threadIdx.x;
  const float* wrow = Wq + (size_t)l * 65536 + (size_t)k * 256;
  float s0 = 0.f, s1 = 0.f, s2 = 0.f, s3 = 0.f;
  for (int c = 0; c < 256; c++){
    float wv = wrow[c];
    s0 += wv * We_s[c];
    s1 += wv * We_s[256 + c];
    s2 += wv * We_s[512 + c];
    s3 += wv * We_s[768 + c];
  }
  float4 o; o.x = s0; o.y = s1; o.z = s2; o.w = s3;
  *(float4*)&Wqe[((size_t)l * 256 + k) * 4] = o;
  if (k < 4){
    float b = 0.f;
    for (int c = 0; c < 256; c++) b += bq[l * 256 + c] * We_s[k * 256 + c];
    bqe[l * 4 + k] = b;
  }
}

// ---------------- qwe for conv1 ----------------
__global__ __launch_bounds__(256) void qwe1_kernel(const _Float16* __restrict__ qkvh,
                                                   const float* __restrict__ We1,
                                                   float* __restrict__ qwe, int N){
  __shared__ float We_s[1024];
  for (int i = threadIdx.x; i < 1024; i += 256) We_s[i] = We1[i];
  __syncthreads();
  int wid = threadIdx.x >> 6, lane = threadIdx.x & 63;
  int n = blockIdx.x * 4 + wid;
  if (n >= N) return;
  int c0 = lane * 4;
  h16x4 qr = *(const h16x4*)&qkvh[(size_t)n * 768 + c0];
  float q0 = (float)qr[0], q1 = (float)qr[1], q2 = (float)qr[2], q3 = (float)qr[3];
  float4 o;
  #pragma unroll
  for (int j = 0; j < 4; j++){
    float s = q0 * We_s[j * 256 + c0] + q1 * We_s[j * 256 + c0 + 1]
            + q2 * We_s[j * 256 + c0 + 2] + q3 * We_s[j * 256 + c0 + 3];
    s = wred_sum(s);
    if (j == 0) o.x = s; else if (j == 1) o.y = s; else if (j == 2) o.z = s; else o.w = s;
  }
  if (lane == 0) *(float4*)&qwe[(size_t)n * 4] = o;
}

// ---------------- conv1 GEMMs ----------------
__global__ __launch_bounds__(256) void gemm1_kernel(
    const float* __restrict__ A,
    const float* __restrict__ W0, const float* __restrict__ W1,
    const float* __restrict__ W2, const float* __restrict__ W3,
    const float* __restrict__ B0, const float* __restrict__ B1,
    const float* __restrict__ B2, const float* __restrict__ B3,
    _Float16* __restrict__ qkvh, _Float16* __restrict__ slh, int N)
{
  __shared__ float As[64][16];
  int nb = blockIdx.x * 64;
  {
    int row = nb + (threadIdx.x >> 2);
    int qq = (threadIdx.x & 3) * 4;
    float4 a = make_float4(0.f, 0.f, 0.f, 0.f);
    if (row < N) a = *(const float4*)&A[row * 16 + qq];
    *(float4*)&As[threadIdx.x >> 2][qq] = a;
  }
  __syncthreads();
  int col = threadIdx.x;
  #pragma unroll
  for (int w = 0; w < 4; w++){
    const float* W  = (w == 0) ? W0 : (w == 1) ? W1 : (w == 2) ? W2 : W3;
    const float* Bi = (w == 0) ? B0 : (w == 1) ? B1 : (w == 2) ? B2 : B3;
    float wr[16];
    #pragma unroll
    for (int kk = 0; kk < 16; kk++) wr[kk] = W[kk * 256 + col];
    float bias = Bi[col];
    for (int r = 0; r < 64; r++){
      int row = nb + r;
      if (row >= N) break;
      float acc = bias;
      #pragma unroll
      for (int kk = 0; kk < 16; kk++) acc += As[r][kk] * wr[kk];
      if (w < 3) qkvh[(size_t)row * 768 + w * 256 + col] = (_Float16)acc;
      else       slh[(size_t)row * 256 + col] = (_Float16)acc;
    }
  }
}

// ---------------- main MFMA GEMM (XCD-swizzled, LDS-staged epilogue) ----------------
__global__ __launch_bounds__(256, 3) void gemm_mfma_kernel(
    const unsigned short* __restrict__ A,
    const unsigned short* __restrict__ Wp,
    const float* __restrict__ bp,
    _Float16* __restrict__ qkvh,
    _Float16* __restrict__ slh,
    int M)
{
  __shared__ unsigned short lds[2 * 128 * 64];
  unsigned short* ldsA = lds;
  unsigned short* ldsB = lds + 128 * 64;
  const int tid  = threadIdx.x;
  const int wave = tid >> 6, lane = tid & 63;
  const int wm = wave >> 1, wn = wave & 1;
  const int rt  = (int)gridDim.x;
  const int lin = (int)blockIdx.x + rt * (int)blockIdx.y;
  const int gt  = (lin & 7) * rt + (lin >> 3);
  const int m0 = (gt >> 3) * 128;
  const int n0 = (gt & 7) * 128;

  f32x4 acc[4][4] = {};

  const int srow  = lane >> 3;
  const int sc16  = lane & 7;
  const int skgrp = sc16 ^ (srow & 7);

  for (int k0 = 0; k0 < 256; k0 += 64){
    #pragma unroll
    for (int it = 0; it < 4; ++it){
      int lrow = wave * 32 + it * 8;
      const unsigned short* gA = A + (size_t)(m0 + lrow + srow) * 256 + k0 + skgrp * 8;
      __builtin_amdgcn_global_load_lds((const __attribute__((address_space(1))) unsigned int*)gA,
          (__attribute__((address_space(3))) unsigned int*)(ldsA + lrow * 64), 16, 0, 0);
      const unsigned short* gB = Wp + (size_t)(n0 + lrow + srow) * 256 + k0 + skgrp * 8;
      __builtin_amdgcn_global_load_lds((const __attribute__((address_space(1))) unsigned int*)gB,
          (__attribute__((address_space(3))) unsigned int*)(ldsB + lrow * 64), 16, 0, 0);
    }
    __syncthreads();

    bf16x8 af[4][2], bfr[4][2];
    #pragma unroll
    for (int mb = 0; mb < 4; ++mb){
      int r = wm * 64 + mb * 16 + (lane & 15);
      #pragma unroll
      for (int ks = 0; ks < 2; ++ks){
        int kg = ks * 4 + (lane >> 4);
        af[mb][ks] = *(const bf16x8*)&ldsA[r * 64 + ((kg ^ (r & 7)) * 8)];
      }
    }
    #pragma unroll
    for (int nb = 0; nb < 4; ++nb){
      int r = wn * 64 + nb * 16 + (lane & 15);
      #pragma unroll
      for (int ks = 0; ks < 2; ++ks){
        int kg = ks * 4 + (lane >> 4);
        bfr[nb][ks] = *(const bf16x8*)&ldsB[r * 64 + ((kg ^ (r & 7)) * 8)];
      }
    }
    #pragma unroll
    for (int mb = 0; mb < 4; ++mb){
      #pragma unroll
      for (int nb = 0; nb < 4; ++nb){
        acc[mb][nb] = __builtin_amdgcn_mfma_f32_16x16x32_bf16(af[mb][0], bfr[nb][0], acc[mb][nb], 0, 0, 0);
        acc[mb][nb] = __builtin_amdgcn_mfma_f32_16x16x32_bf16(af[mb][1], bfr[nb][1], acc[mb][nb], 0, 0, 0);
      }
    }
    __syncthreads();
  }

  _Float16* lt = (_Float16*)lds;   // [128][128], col ^ ((row>>2)&3)<<4
  #pragma unroll
  for (int nb = 0; nb < 4; ++nb){
    int col = wn * 64 + nb * 16 + (lane & 15);
    float bias = bp[n0 + col];
    #pragma unroll
    for (int mb = 0; mb < 4; ++mb){
      #pragma unroll
      for (int r4 = 0; r4 < 4; ++r4){
        int row = wm * 64 + mb * 16 + (lane >> 4) * 4 + r4;
        lt[row * 128 + (col ^ (((row >> 2) & 3) << 4))] = (_Float16)(acc[mb][nb][r4] + bias);
      }
    }
  }
  __syncthreads();
  int tr = tid >> 4;
  int tc = (tid & 15) * 8;
  if (n0 < 768){
    #pragma unroll
    for (int it = 0; it < 8; ++it){
      int row = tr + it * 16;
      int grow = m0 + row;
      if (grow < M){
        h16x8 v8 = *(const h16x8*)&lt[row * 128 + (tc ^ (((row >> 2) & 3) << 4))];
        *(h16x8*)&qkvh[(size_t)grow * 768 + n0 + tc] = v8;
      }
    }
  } else {
    #pragma unroll
    for (int it = 0; it < 8; ++it){
      int row = tr + it * 16;
      int grow = m0 + row;
      if (grow < M){
        h16x8 v8 = *(const h16x8*)&lt[row * 128 + (tc ^ (((row >> 2) & 3) << 4))];
        *(h16x8*)&slh[(size_t)grow * 256 + (n0 - 768) + tc] = v8;
      }
    }
  }
}

// ---------------- fused attention aggregation (+head on last layer) ----------------
// One wave/node, 8 edge-slots x 8 lanes x 32ch. Fixed-offset softmax:
// w = exp(alpha - 20); the constant cancels in a/ssum exactly, so no online max
// and no cross-chunk rescale -> chunks are pure accumulation (shorter chain).
__global__ __launch_bounds__(512) void agg_kernel(
    const _Float16* __restrict__ qkvh,
    const _Float16* __restrict__ slh,
    const float* __restrict__ qwe,
    const float* __restrict__ ea_csr,
    const int* __restrict__ src_csr,
    const float* __restrict__ We,
    const float* __restrict__ Wqe_next,
    const float* __restrict__ bqe_next,
    const int* __restrict__ row_ptr,
    const _Float16* __restrict__ h_in, _Float16* __restrict__ h_out,
    unsigned short* __restrict__ h2b, float* __restrict__ qwe_out,
    const float* __restrict__ wlsc, float* __restrict__ out,
    int RESID, int LAST, int N)
{
  int wid = threadIdx.x >> 6, lane = threadIdx.x & 63;
  int n = blockIdx.x * 8 + wid;
  if (n >= N) return;
  int c0 = lane * 4;
  int glane = lane >> 3;          // edge slot 0..7
  int slane = lane & 7;           // channel group (32 ch each)
  union hu { h16x8 v; h16x2 p[4]; };

  int e0 = row_ptr[n], e1 = row_ptr[n + 1];
  float4 qwe4 = *(const float4*)&qwe[(size_t)n * 4];
  h16x4 slv4 = *(const h16x4*)&slh[(size_t)n * 256 + c0];
  h16x4 hpv = {};
  if (RESID) hpv = *(const h16x4*)&h_in[(size_t)n * 256 + c0];
  const _Float16* qrow = qkvh + (size_t)n * 768 + slane * 32;
  hu qf[4];
  #pragma unroll
  for (int u = 0; u < 4; ++u) qf[u].v = *(const h16x8*)(qrow + u * 8);

  float ssum = 0.f;
  float a0 = 0.f, a1 = 0.f, a2 = 0.f, a3 = 0.f;
  float ec0 = 0.f, ec1 = 0.f, ec2 = 0.f, ec3 = 0.f;

  for (int base = e0; base < e1; base += 8){
    int cnt = min(8, e1 - base);
    int eg = base + ((glane < cnt) ? glane : (cnt - 1));
    int sg = src_csr[eg];
    float4 eag = *(const float4*)&ea_csr[(size_t)eg * 4];
    const _Float16* krow = qkvh + (size_t)sg * 768 + 256 + slane * 32;
    float dot = 0.f;
    #pragma unroll
    for (int u = 0; u < 4; ++u){
      hu kf;
      kf.v = *(const h16x8*)(krow + u * 8);
      #pragma unroll
      for (int pp = 0; pp < 4; ++pp){
#if __has_builtin(__builtin_amdgcn_fdot2)
        dot = __builtin_amdgcn_fdot2(qf[u].p[pp], kf.p[pp], dot, false);
#else
        dot += (float)qf[u].p[pp][0] * (float)kf.p[pp][0] + (float)qf[u].p[pp][1] * (float)kf.p[pp][1];
#endif
      }
    }
    #pragma unroll
    for (int o = 1; o < 8; o <<= 1) dot += __shfl_xor(dot, o, 64);
    // fixed-offset weight; identical ratio to reference softmax
    float w_g = expf((dot + qwe4.x * eag.x + qwe4.y * eag.y + qwe4.z * eag.z + qwe4.w * eag.w)
                     * 0.0625f - 20.f);
    int sg_bc = sg;
    #pragma unroll
    for (int j = 0; j < 8; ++j){
      if (j < cnt){
        float wj = __shfl(w_g, j << 3, 64);
        int sj = __shfl(sg_bc, j << 3, 64);
        h16x4 vr = *(const h16x4*)&qkvh[(size_t)sj * 768 + 512 + c0];
        float4 er = *(const float4*)&ea_csr[(size_t)(base + j) * 4];
        ssum += wj;
        a0 += wj * (float)vr[0];
        a1 += wj * (float)vr[1];
        a2 += wj * (float)vr[2];
        a3 += wj * (float)vr[3];
        ec0 += wj * er.x;
        ec1 += wj * er.y;
        ec2 += wj * er.z;
        ec3 += wj * er.w;
      }
    }
  }
  ssum *= 0.125f;   // each lane added its slot's w 1x, but all 8 slots' w were
                    // accumulated by every lane -> ssum counted 8x? No: each lane
                    // adds each wj exactly once (j loop) -> ssum = 8x sum/8... 
  // CORRECTNESS: every lane accumulates wj for ALL j slots once -> ssum is the
  // true sum (each wj added once per lane). The 0.125 scale above would be wrong.
  ssum *= 8.f;      // revert (net no-op, kept for clarity of the reasoning above)

  float inv = 1.f / (ssum + 1e-16f);
  float4 W0 = *(const float4*)&We[0 * 256 + c0];
  float4 W1 = *(const float4*)&We[1 * 256 + c0];
  float4 W2 = *(const float4*)&We[2 * 256 + c0];
  float4 W3 = *(const float4*)&We[3 * 256 + c0];
  float emb0 = ec0 * W0.x + ec1 * W1.x + ec2 * W2.x + ec3 * W3.x;
  float emb1 = ec0 * W0.y + ec1 * W1.y + ec2 * W2.y + ec3 * W3.y;
  float emb2 = ec0 * W0.z + ec1 * W1.z + ec2 * W2.z + ec3 * W3.z;
  float emb3 = ec0 * W0.w + ec1 * W1.w + ec2 * W2.w + ec3 * W3.w;
  float y0 = (a0 + emb0) * inv + (float)slv4[0];
  float y1 = (a1 + emb1) * inv + (float)slv4[1];
  float y2 = (a2 + emb2) * inv + (float)slv4[2];
  float y3 = (a3 + emb3) * inv + (float)slv4[3];
  float o0 = y0, o1 = y1, o2 = y2, o3 = y3;
  if (RESID){
    o0 += (float)hpv[0]; o1 += (float)hpv[1]; o2 += (float)hpv[2]; o3 += (float)hpv[3];
  }
  if (LAST){
    float4 wv = *(const float4*)&wlsc[c0];
    float pp = o0 * wv.x + o1 * wv.y + o2 * wv.z + o3 * wv.w;
    pp = wred_sum(pp);
    if (lane == 0) out[n] = pp * (1.f / sqrtf(15.f)) + wlsc[256];
    return;
  }
  h16x4 ho;
  ho[0] = (_Float16)o0; ho[1] = (_Float16)o1; ho[2] = (_Float16)o2; ho[3] = (_Float16)o3;
  *(h16x4*)&h_out[(size_t)n * 256 + c0] = ho;
  float mean = wred_sum(o0 + o1 + o2 + o3) * (1.f / 256.f);
  float d0 = o0 - mean, d1 = o1 - mean, d2 = o2 - mean, d3 = o3 - mean;
  float var = wred_sum(d0 * d0 + d1 * d1 + d2 * d2 + d3 * d3) * (1.f / 255.f);
  float invstd = 1.f / sqrtf(var);
  float t0 = fmaxf(o0 * invstd, 0.f);
  float t1 = fmaxf(o1 * invstd, 0.f);
  float t2 = fmaxf(o2 * invstd, 0.f);
  float t3 = fmaxf(o3 * invstd, 0.f);
  ushort4 hb;
  hb.x = f2bf(t0); hb.y = f2bf(t1); hb.z = f2bf(t2); hb.w = f2bf(t3);
  *(ushort4*)&h2b[(size_t)n * 256 + c0] = hb;
  if (Wqe_next){
    float4 g0 = *(const float4*)&Wqe_next[(c0 + 0) * 4];
    float4 g1 = *(const float4*)&Wqe_next[(c0 + 1) * 4];
    float4 g2 = *(const float4*)&Wqe_next[(c0 + 2) * 4];
    float4 g3 = *(const float4*)&Wqe_next[(c0 + 3) * 4];
    float s0 = t0 * g0.x + t1 * g1.x + t2 * g2.x + t3 * g3.x;
    float s1 = t0 * g0.y + t1 * g1.y + t2 * g2.y + t3 * g3.y;
    float s2 = t0 * g0.z + t1 * g1.z + t2 * g2.z + t3 * g3.z;
    float s3 = t0 * g0.w + t1 * g1.w + t2 * g2.w + t3 * g3.w;
    s0 = wred_sum(s0); s1 = wred_sum(s1); s2 = wred_sum(s2); s3 = wred_sum(s3);
    if (lane == 0){
      float4 bq4 = *(const float4*)bqe_next;
      float4 o; o.x = s0 + bq4.x; o.y = s1 + bq4.y; o.z = s2 + bq4.z; o.w = s3 + bq4.w;
      *(float4*)&qwe_out[(size_t)n * 4] = o;
    }
  }
}

// ---------------- launch ----------------
extern "C" void kernel_launch(void* const* d_in, const int* in_sizes, int n_in,
                              void* d_out, int out_size, void* d_ws, size_t ws_size,
                              hipStream_t stream)
{
  const float* x     = (const float*)d_in[0];
  const int*   eidx  = (const int*)d_in[1];
  const float* Wq1 = (const float*)d_in[3];  const float* bq1 = (const float*)d_in[4];
  const float* Wk1 = (const float*)d_in[5];  const float* bk1 = (const float*)d_in[6];
  const float* Wv1 = (const float*)d_in[7];  const float* bv1 = (const float*)d_in[8];
  const float* We1 = (const float*)d_in[9];
  const float* Ws1 = (const float*)d_in[10]; const float* bs1 = (const float*)d_in[11];
  const float* Wq = (const float*)d_in[12];  const float* bq = (const float*)d_in[13];
  const float* Wk = (const float*)d_in[14];  const float* bk = (const float*)d_in[15];
  const float* Wv = (const float*)d_in[16];  const float* bv = (const float*)d_in[17];
  const float* We = (const float*)d_in[18];
  const float* Ws = (const float*)d_in[19];  const float* bs = (const float*)d_in[20];
  const float* Wl = (const float*)d_in[21];  const float* bl = (const float*)d_in[22];
  const float* scale = (const float*)d_in[23];
  (void)n_in; (void)ws_size;

  int N = in_sizes[0] / 16;
  int E = in_sizes[2] / 4;
  int Mpad = (N + 127) & ~127;
  float* out = (float*)d_out;
  (void)out_size;

  char* p = (char*)d_ws;
  auto alloc = [&](size_t bytes) -> char* {
    char* r = p; p += (bytes + 255) & ~(size_t)255; return r;
  };
  float* hx   = (float*)alloc((size_t)N * 16 * 4);
  float* ea   = (float*)alloc((size_t)E * 4 * 4);
  _Float16* hh = (_Float16*)alloc((size_t)N * 256 * 2);
  unsigned short* h2b = (unsigned short*)alloc((size_t)Mpad * 256 * 2);
  _Float16* qkvh = (_Float16*)alloc((size_t)N * 768 * 2);
  _Float16* slh  = (_Float16*)alloc((size_t)N * 256 * 2);
  float* qwe  = (float*)alloc((size_t)N * 4 * 4);
  float* ea_csr = (float*)alloc((size_t)E * 4 * 4);
  int* src_csr  = (int*)alloc((size_t)E * 4);
  unsigned short* Wp  = (unsigned short*)alloc((size_t)15 * 1024 * 256 * 2);
  float* bp   = (float*)alloc((size_t)15 * 1024 * 4);
  float* Wqe  = (float*)alloc((size_t)15 * 256 * 4 * 4);
  float* bqe  = (float*)alloc((size_t)15 * 4 * 4);
  float* wlsc = (float*)alloc(257 * 4);
  int* counts  = (int*)alloc((size_t)N * 4);
  int* cursor  = (int*)alloc((size_t)N * 4);
  int* row_ptr = (int*)alloc(((size_t)N + 1) * 4);

  const int* srcp = eidx;
  const int* dstp = eidx + E;

  int nx = N * 16, ne = E * 4;
  int big = nx > ne ? nx : ne;

  zero_kernel<<<(N + 255) / 256, 256, 0, stream>>>(counts, N);
  prep_kernel<<<(big + 255) / 256, 256, 0, stream>>>(x, (const float*)d_in[2], hx, ea, nx, ne);
  hist_kernel<<<(E + 255) / 256, 256, 0, stream>>>(dstp, counts, E);
  scan_kernel<<<1, 1024, 0, stream>>>(counts, row_ptr, cursor, N);
  scatter_kernel<<<(E + 255) / 256, 256, 0, stream>>>(srcp, dstp, ea, cursor,
                                                      src_csr, ea_csr, E);
  wlscale_kernel<<<1, 256, 0, stream>>>(Wl, bl, scale, wlsc);
  pack_w_kernel<<<dim3(8, 32, 15), 256, 0, stream>>>(Wq, Wk, Wv, Ws, Wp);
  pack_b_kernel<<<15, 256, 0, stream>>>(bq, bk, bv, bs, bp);
  pack_wqe_kernel<<<15, 256, 0, stream>>>(Wq, We, bq, Wqe, bqe);

  int agg_blocks = (N + 7) / 8;

  // conv1
  gemm1_kernel<<<(N + 63) / 64, 256, 0, stream>>>(hx, Wq1, Wk1, Wv1, Ws1,
                                                  bq1, bk1, bv1, bs1, qkvh, slh, N);
  qwe1_kernel<<<(N + 3) / 4, 256, 0, stream>>>(qkvh, We1, qwe, N);
  agg_kernel<<<agg_blocks, 512, 0, stream>>>(qkvh, slh, qwe, ea_csr, src_csr, We1,
                                             Wqe, bqe, row_ptr,
                                             hh, hh, h2b, qwe, wlsc, out, 0, 0, N);

  // 15 residual blocks
  for (int l = 0; l < 15; l++){
    gemm_mfma_kernel<<<dim3(Mpad / 128, 8), 256, 0, stream>>>(
        h2b, Wp + (size_t)l * 262144, bp + (size_t)l * 1024, qkvh, slh, N);
    int last = (l == 14);
    const float* wqe_n = (l < 14) ? (Wqe + (size_t)(l + 1) * 1024) : nullptr;
    const float* bqe_n = (l < 14) ? (bqe + (size_t)(l + 1) * 4) : nullptr;
    agg_kernel<<<agg_blocks, 512, 0, stream>>>(qkvh, slh, qwe, ea_csr, src_csr,
                                               We + (size_t)l * 1024,
                                               wqe_n, bqe_n, row_ptr,
                                               hh, hh, h2b, qwe, wlsc, out, 1, last, N);
  }
}

// Round 15
// 1038.931 us; speedup vs baseline: 1.1214x; 1.0016x over previous
//
#include <hip/hip_runtime.h>
#include <math.h>

typedef short bf16x8 __attribute__((ext_vector_type(8)));
typedef float f32x4 __attribute__((ext_vector_type(4)));
typedef _Float16 h16x8 __attribute__((ext_vector_type(8)));
typedef _Float16 h16x4 __attribute__((ext_vector_type(4)));
typedef _Float16 h16x2 __attribute__((ext_vector_type(2)));

static __device__ __forceinline__ float wred_sum(float v){
  #pragma unroll
  for (int o = 32; o > 0; o >>= 1) v += __shfl_xor(v, o, 64);
  return v;
}

static __device__ __forceinline__ unsigned short f2bf(float x){
  union { float f; unsigned int u; } c; c.f = x;
  unsigned int u = c.u;
  return (unsigned short)((u + 0x7FFFu + ((u >> 16) & 1u)) >> 16);
}

// ---------------- prep + histogram (fused) ----------------
__global__ void prep_hist_kernel(const float* __restrict__ x, const float* __restrict__ ea_in,
                                 const int* __restrict__ dst,
                                 float* __restrict__ hx, float* __restrict__ ea,
                                 int* __restrict__ counts,
                                 int nx, int ne, int E){
  int i = blockIdx.x * 256 + threadIdx.x;
  if (i < nx) hx[i] = logf(x[i] + 1.f);
  if (i < ne) ea[i] = logf(ea_in[i] + 1.f);
  if (i < E) atomicAdd(&counts[dst[i]], 1);
}

// wave-shfl hierarchical scan
__global__ __launch_bounds__(1024) void scan_kernel(const int* __restrict__ counts,
                                                    int* __restrict__ row_ptr,
                                                    int* __restrict__ cursor, int N){
  __shared__ int woff[16];
  __shared__ int carry_s;
  int t = threadIdx.x, lane = t & 63, wid = t >> 6;
  if (t == 0) carry_s = 0;
  __syncthreads();
  for (int base = 0; base < N; base += 1024){
    int i = base + t;
    int v = (i < N) ? counts[i] : 0;
    int incl = v;
    #pragma unroll
    for (int o = 1; o < 64; o <<= 1){
      int tmp = __shfl_up(incl, o, 64);
      if (lane >= o) incl += tmp;
    }
    if (lane == 63) woff[wid] = incl;
    __syncthreads();
    if (t < 16){
      int w = woff[t];
      int inc2 = w;
      #pragma unroll
      for (int o = 1; o < 16; o <<= 1){
        int tmp = __shfl_up(inc2, o, 16);
        if (t >= o) inc2 += tmp;
      }
      woff[t] = inc2 - w;
    }
    __syncthreads();
    int ex = carry_s + woff[wid] + incl - v;
    if (i < N){ row_ptr[i] = ex; cursor[i] = ex; }
    __syncthreads();
    if (t == 1023) carry_s = ex + v;
    __syncthreads();
  }
  if (t == 0) row_ptr[N] = carry_s;
}

__global__ void scatter_kernel(const int* __restrict__ src, const int* __restrict__ dst,
                               const float* __restrict__ ea,
                               int* __restrict__ cursor,
                               int* __restrict__ src_csr, float* __restrict__ ea_csr, int E){
  int i = blockIdx.x * 256 + threadIdx.x;
  if (i < E){
    int p = atomicAdd(&cursor[dst[i]], 1);
    src_csr[p] = src[i];
    *(float4*)&ea_csr[(size_t)p * 4] = *(const float4*)&ea[(size_t)i * 4];
  }
}

// ---------------- weight pack (bf16 W^T for MFMA) ----------------
__global__ __launch_bounds__(256) void pack_w_kernel(
    const float* __restrict__ Wq, const float* __restrict__ Wk,
    const float* __restrict__ Wv, const float* __restrict__ Ws,
    unsigned short* __restrict__ Wp)
{
  __shared__ float t[32][33];
  int l   = blockIdx.z;
  int k0  = blockIdx.x * 32;
  int n0g = blockIdx.y * 32;
  int w   = n0g >> 8;
  int n0  = n0g & 255;
  const float* W = ((w == 0) ? Wq : (w == 1) ? Wk : (w == 2) ? Wv : Ws) + (size_t)l * 65536;
  int rr = threadIdx.x >> 3;
  int cc = (threadIdx.x & 7) * 4;
  float4 vv = *(const float4*)&W[(size_t)(k0 + rr) * 256 + n0 + cc];
  t[rr][cc + 0] = vv.x; t[rr][cc + 1] = vv.y; t[rr][cc + 2] = vv.z; t[rr][cc + 3] = vv.w;
  __syncthreads();
  ushort4 o;
  o.x = f2bf(t[cc + 0][rr]);
  o.y = f2bf(t[cc + 1][rr]);
  o.z = f2bf(t[cc + 2][rr]);
  o.w = f2bf(t[cc + 3][rr]);
  *(ushort4*)&Wp[(size_t)l * 262144 + (size_t)(n0g + rr) * 256 + k0 + cc] = o;
}

// ---------------- pack Wqe (+ fused pack_b / wlscale in block 15) ----------------
__global__ __launch_bounds__(256) void pack_wqe_kernel(
    const float* __restrict__ Wq, const float* __restrict__ We,
    const float* __restrict__ bq, float* __restrict__ Wqe, float* __restrict__ bqe,
    const float* __restrict__ bk, const float* __restrict__ bv,
    const float* __restrict__ bs, float* __restrict__ bp,
    const float* __restrict__ Wl, const float* __restrict__ bl,
    const float* __restrict__ scale, float* __restrict__ wlsc)
{
  int l = blockIdx.x;
  if (l == 15){
    // pack biases: bp[l][q|k|v|s]
    int c = threadIdx.x;
    for (int ll = 0; ll < 15; ++ll){
      int i = ll * 256 + c;
      bp[ll * 1024 + 0   + c] = bq[i];
      bp[ll * 1024 + 256 + c] = bk[i];
      bp[ll * 1024 + 512 + c] = bv[i];
      bp[ll * 1024 + 768 + c] = bs[i];
    }
    // head: wlsc
    float s = 0.f;
    #pragma unroll
    for (int j = 0; j < 8; j++) s += Wl[c * 8 + j] * scale[j];
    wlsc[c] = s;
    if (c == 0){
      float b = 0.f;
      #pragma unroll
      for (int j = 0; j < 8; j++) b += bl[j] * scale[j];
      wlsc[256] = b;
    }
    return;
  }
  __shared__ float We_s[1024];
  for (int i = threadIdx.x; i < 1024; i += 256) We_s[i] = We[(size_t)l * 1024 + i];
  __syncthreads();
  int k = threadIdx.x;
  const float* wrow = Wq + (size_t)l * 65536 + (size_t)k * 256;
  float s0 = 0.f, s1 = 0.f, s2 = 0.f, s3 = 0.f;
  for (int c = 0; c < 256; c++){
    float wv = wrow[c];
    s0 += wv * We_s[c];
    s1 += wv * We_s[256 + c];
    s2 += wv * We_s[512 + c];
    s3 += wv * We_s[768 + c];
  }
  float4 o; o.x = s0; o.y = s1; o.z = s2; o.w = s3;
  *(float4*)&Wqe[((size_t)l * 256 + k) * 4] = o;
  if (k < 4){
    float b = 0.f;
    for (int c = 0; c < 256; c++) b += bq[l * 256 + c] * We_s[k * 256 + c];
    bqe[l * 4 + k] = b;
  }
}

// ---------------- qwe for conv1 ----------------
__global__ __launch_bounds__(256) void qwe1_kernel(const _Float16* __restrict__ qkvh,
                                                   const float* __restrict__ We1,
                                                   float* __restrict__ qwe, int N){
  __shared__ float We_s[1024];
  for (int i = threadIdx.x; i < 1024; i += 256) We_s[i] = We1[i];
  __syncthreads();
  int wid = threadIdx.x >> 6, lane = threadIdx.x & 63;
  int n = blockIdx.x * 4 + wid;
  if (n >= N) return;
  int c0 = lane * 4;
  h16x4 qr = *(const h16x4*)&qkvh[(size_t)n * 768 + c0];
  float q0 = (float)qr[0], q1 = (float)qr[1], q2 = (float)qr[2], q3 = (float)qr[3];
  float4 o;
  #pragma unroll
  for (int j = 0; j < 4; j++){
    float s = q0 * We_s[j * 256 + c0] + q1 * We_s[j * 256 + c0 + 1]
            + q2 * We_s[j * 256 + c0 + 2] + q3 * We_s[j * 256 + c0 + 3];
    s = wred_sum(s);
    if (j == 0) o.x = s; else if (j == 1) o.y = s; else if (j == 2) o.z = s; else o.w = s;
  }
  if (lane == 0) *(float4*)&qwe[(size_t)n * 4] = o;
}

// ---------------- conv1 GEMMs ----------------
__global__ __launch_bounds__(256) void gemm1_kernel(
    const float* __restrict__ A,
    const float* __restrict__ W0, const float* __restrict__ W1,
    const float* __restrict__ W2, const float* __restrict__ W3,
    const float* __restrict__ B0, const float* __restrict__ B1,
    const float* __restrict__ B2, const float* __restrict__ B3,
    _Float16* __restrict__ qkvh, _Float16* __restrict__ slh, int N)
{
  __shared__ float As[64][16];
  int nb = blockIdx.x * 64;
  {
    int row = nb + (threadIdx.x >> 2);
    int qq = (threadIdx.x & 3) * 4;
    float4 a = make_float4(0.f, 0.f, 0.f, 0.f);
    if (row < N) a = *(const float4*)&A[row * 16 + qq];
    *(float4*)&As[threadIdx.x >> 2][qq] = a;
  }
  __syncthreads();
  int col = threadIdx.x;
  #pragma unroll
  for (int w = 0; w < 4; w++){
    const float* W  = (w == 0) ? W0 : (w == 1) ? W1 : (w == 2) ? W2 : W3;
    const float* Bi = (w == 0) ? B0 : (w == 1) ? B1 : (w == 2) ? B2 : B3;
    float wr[16];
    #pragma unroll
    for (int kk = 0; kk < 16; kk++) wr[kk] = W[kk * 256 + col];
    float bias = Bi[col];
    for (int r = 0; r < 64; r++){
      int row = nb + r;
      if (row >= N) break;
      float acc = bias;
      #pragma unroll
      for (int kk = 0; kk < 16; kk++) acc += As[r][kk] * wr[kk];
      if (w < 3) qkvh[(size_t)row * 768 + w * 256 + col] = (_Float16)acc;
      else       slh[(size_t)row * 256 + col] = (_Float16)acc;
    }
  }
}

// ---------------- main MFMA GEMM (XCD-swizzled, LDS-staged epilogue) ----------------
__global__ __launch_bounds__(256, 3) void gemm_mfma_kernel(
    const unsigned short* __restrict__ A,
    const unsigned short* __restrict__ Wp,
    const float* __restrict__ bp,
    _Float16* __restrict__ qkvh,
    _Float16* __restrict__ slh,
    int M)
{
  __shared__ unsigned short lds[2 * 128 * 64];
  unsigned short* ldsA = lds;
  unsigned short* ldsB = lds + 128 * 64;
  const int tid  = threadIdx.x;
  const int wave = tid >> 6, lane = tid & 63;
  const int wm = wave >> 1, wn = wave & 1;
  const int rt  = (int)gridDim.x;
  const int lin = (int)blockIdx.x + rt * (int)blockIdx.y;
  const int gt  = (lin & 7) * rt + (lin >> 3);
  const int m0 = (gt >> 3) * 128;
  const int n0 = (gt & 7) * 128;

  f32x4 acc[4][4] = {};

  const int srow  = lane >> 3;
  const int sc16  = lane & 7;
  const int skgrp = sc16 ^ (srow & 7);

  for (int k0 = 0; k0 < 256; k0 += 64){
    #pragma unroll
    for (int it = 0; it < 4; ++it){
      int lrow = wave * 32 + it * 8;
      const unsigned short* gA = A + (size_t)(m0 + lrow + srow) * 256 + k0 + skgrp * 8;
      __builtin_amdgcn_global_load_lds((const __attribute__((address_space(1))) unsigned int*)gA,
          (__attribute__((address_space(3))) unsigned int*)(ldsA + lrow * 64), 16, 0, 0);
      const unsigned short* gB = Wp + (size_t)(n0 + lrow + srow) * 256 + k0 + skgrp * 8;
      __builtin_amdgcn_global_load_lds((const __attribute__((address_space(1))) unsigned int*)gB,
          (__attribute__((address_space(3))) unsigned int*)(ldsB + lrow * 64), 16, 0, 0);
    }
    __syncthreads();

    bf16x8 af[4][2], bfr[4][2];
    #pragma unroll
    for (int mb = 0; mb < 4; ++mb){
      int r = wm * 64 + mb * 16 + (lane & 15);
      #pragma unroll
      for (int ks = 0; ks < 2; ++ks){
        int kg = ks * 4 + (lane >> 4);
        af[mb][ks] = *(const bf16x8*)&ldsA[r * 64 + ((kg ^ (r & 7)) * 8)];
      }
    }
    #pragma unroll
    for (int nb = 0; nb < 4; ++nb){
      int r = wn * 64 + nb * 16 + (lane & 15);
      #pragma unroll
      for (int ks = 0; ks < 2; ++ks){
        int kg = ks * 4 + (lane >> 4);
        bfr[nb][ks] = *(const bf16x8*)&ldsB[r * 64 + ((kg ^ (r & 7)) * 8)];
      }
    }
    #pragma unroll
    for (int mb = 0; mb < 4; ++mb){
      #pragma unroll
      for (int nb = 0; nb < 4; ++nb){
        acc[mb][nb] = __builtin_amdgcn_mfma_f32_16x16x32_bf16(af[mb][0], bfr[nb][0], acc[mb][nb], 0, 0, 0);
        acc[mb][nb] = __builtin_amdgcn_mfma_f32_16x16x32_bf16(af[mb][1], bfr[nb][1], acc[mb][nb], 0, 0, 0);
      }
    }
    __syncthreads();
  }

  _Float16* lt = (_Float16*)lds;   // [128][128], col ^ ((row>>2)&3)<<4
  #pragma unroll
  for (int nb = 0; nb < 4; ++nb){
    int col = wn * 64 + nb * 16 + (lane & 15);
    float bias = bp[n0 + col];
    #pragma unroll
    for (int mb = 0; mb < 4; ++mb){
      #pragma unroll
      for (int r4 = 0; r4 < 4; ++r4){
        int row = wm * 64 + mb * 16 + (lane >> 4) * 4 + r4;
        lt[row * 128 + (col ^ (((row >> 2) & 3) << 4))] = (_Float16)(acc[mb][nb][r4] + bias);
      }
    }
  }
  __syncthreads();
  int tr = tid >> 4;
  int tc = (tid & 15) * 8;
  if (n0 < 768){
    #pragma unroll
    for (int it = 0; it < 8; ++it){
      int row = tr + it * 16;
      int grow = m0 + row;
      if (grow < M){
        h16x8 v8 = *(const h16x8*)&lt[row * 128 + (tc ^ (((row >> 2) & 3) << 4))];
        *(h16x8*)&qkvh[(size_t)grow * 768 + n0 + tc] = v8;
      }
    }
  } else {
    #pragma unroll
    for (int it = 0; it < 8; ++it){
      int row = tr + it * 16;
      int grow = m0 + row;
      if (grow < M){
        h16x8 v8 = *(const h16x8*)&lt[row * 128 + (tc ^ (((row >> 2) & 3) << 4))];
        *(h16x8*)&slh[(size_t)grow * 256 + (n0 - 768) + tc] = v8;
      }
    }
  }
}

// ---------------- fused attention aggregation (+head on last layer) ----------------
__global__ __launch_bounds__(512) void agg_kernel(
    const _Float16* __restrict__ qkvh,
    const _Float16* __restrict__ slh,
    const float* __restrict__ qwe,
    const float* __restrict__ ea_csr,
    const int* __restrict__ src_csr,
    const float* __restrict__ We,
    const float* __restrict__ Wqe_next,
    const float* __restrict__ bqe_next,
    const int* __restrict__ row_ptr,
    const _Float16* __restrict__ h_in, _Float16* __restrict__ h_out,
    unsigned short* __restrict__ h2b, float* __restrict__ qwe_out,
    const float* __restrict__ wlsc, float* __restrict__ out,
    int RESID, int LAST, int N)
{
  int wid = threadIdx.x >> 6, lane = threadIdx.x & 63;
  int n = blockIdx.x * 8 + wid;
  if (n >= N) return;
  int c0 = lane * 4;
  int glane = lane >> 3;          // edge slot 0..7
  int slane = lane & 7;           // channel group (32 ch each)
  union hu { h16x8 v; h16x2 p[4]; };

  int e0 = row_ptr[n], e1 = row_ptr[n + 1];
  float4 qwe4 = *(const float4*)&qwe[(size_t)n * 4];
  h16x4 slv4 = *(const h16x4*)&slh[(size_t)n * 256 + c0];
  h16x4 hpv = {};
  if (RESID) hpv = *(const h16x4*)&h_in[(size_t)n * 256 + c0];
  const _Float16* qrow = qkvh + (size_t)n * 768 + slane * 32;
  hu qf[4];
  #pragma unroll
  for (int u = 0; u < 4; ++u) qf[u].v = *(const h16x8*)(qrow + u * 8);

  float ssum = 0.f;
  float a0 = 0.f, a1 = 0.f, a2 = 0.f, a3 = 0.f;
  float ec0 = 0.f, ec1 = 0.f, ec2 = 0.f, ec3 = 0.f;

  for (int base = e0; base < e1; base += 8){
    int cnt = min(8, e1 - base);
    int eg = base + ((glane < cnt) ? glane : (cnt - 1));
    int sg = src_csr[eg];
    float4 eag = *(const float4*)&ea_csr[(size_t)eg * 4];
    const _Float16* krow = qkvh + (size_t)sg * 768 + 256 + slane * 32;
    float dot = 0.f;
    #pragma unroll
    for (int u = 0; u < 4; ++u){
      hu kf;
      kf.v = *(const h16x8*)(krow + u * 8);
      #pragma unroll
      for (int pp = 0; pp < 4; ++pp){
#if __has_builtin(__builtin_amdgcn_fdot2)
        dot = __builtin_amdgcn_fdot2(qf[u].p[pp], kf.p[pp], dot, false);
#else
        dot += (float)qf[u].p[pp][0] * (float)kf.p[pp][0] + (float)qf[u].p[pp][1] * (float)kf.p[pp][1];
#endif
      }
    }
    #pragma unroll
    for (int o = 1; o < 8; o <<= 1) dot += __shfl_xor(dot, o, 64);
    // fixed-offset weight; constant cancels exactly in a/ssum ratio
    float w_g = expf((dot + qwe4.x * eag.x + qwe4.y * eag.y + qwe4.z * eag.z + qwe4.w * eag.w)
                     * 0.0625f - 20.f);
    int sg_bc = sg;
    #pragma unroll
    for (int j = 0; j < 8; ++j){
      if (j < cnt){
        float wj = __shfl(w_g, j << 3, 64);
        int sj = __shfl(sg_bc, j << 3, 64);
        h16x4 vr = *(const h16x4*)&qkvh[(size_t)sj * 768 + 512 + c0];
        float4 er = *(const float4*)&ea_csr[(size_t)(base + j) * 4];
        ssum += wj;
        a0 += wj * (float)vr[0];
        a1 += wj * (float)vr[1];
        a2 += wj * (float)vr[2];
        a3 += wj * (float)vr[3];
        ec0 += wj * er.x;
        ec1 += wj * er.y;
        ec2 += wj * er.z;
        ec3 += wj * er.w;
      }
    }
  }

  float inv = 1.f / (ssum + 1e-16f);
  float4 W0 = *(const float4*)&We[0 * 256 + c0];
  float4 W1 = *(const float4*)&We[1 * 256 + c0];
  float4 W2 = *(const float4*)&We[2 * 256 + c0];
  float4 W3 = *(const float4*)&We[3 * 256 + c0];
  float emb0 = ec0 * W0.x + ec1 * W1.x + ec2 * W2.x + ec3 * W3.x;
  float emb1 = ec0 * W0.y + ec1 * W1.y + ec2 * W2.y + ec3 * W3.y;
  float emb2 = ec0 * W0.z + ec1 * W1.z + ec2 * W2.z + ec3 * W3.z;
  float emb3 = ec0 * W0.w + ec1 * W1.w + ec2 * W2.w + ec3 * W3.w;
  float y0 = (a0 + emb0) * inv + (float)slv4[0];
  float y1 = (a1 + emb1) * inv + (float)slv4[1];
  float y2 = (a2 + emb2) * inv + (float)slv4[2];
  float y3 = (a3 + emb3) * inv + (float)slv4[3];
  float o0 = y0, o1 = y1, o2 = y2, o3 = y3;
  if (RESID){
    o0 += (float)hpv[0]; o1 += (float)hpv[1]; o2 += (float)hpv[2]; o3 += (float)hpv[3];
  }
  if (LAST){
    float4 wv = *(const float4*)&wlsc[c0];
    float pp = o0 * wv.x + o1 * wv.y + o2 * wv.z + o3 * wv.w;
    pp = wred_sum(pp);
    if (lane == 0) out[n] = pp * (1.f / sqrtf(15.f)) + wlsc[256];
    return;
  }
  h16x4 ho;
  ho[0] = (_Float16)o0; ho[1] = (_Float16)o1; ho[2] = (_Float16)o2; ho[3] = (_Float16)o3;
  *(h16x4*)&h_out[(size_t)n * 256 + c0] = ho;
  float mean = wred_sum(o0 + o1 + o2 + o3) * (1.f / 256.f);
  float d0 = o0 - mean, d1 = o1 - mean, d2 = o2 - mean, d3 = o3 - mean;
  float var = wred_sum(d0 * d0 + d1 * d1 + d2 * d2 + d3 * d3) * (1.f / 255.f);
  float invstd = 1.f / sqrtf(var);
  float t0 = fmaxf(o0 * invstd, 0.f);
  float t1 = fmaxf(o1 * invstd, 0.f);
  float t2 = fmaxf(o2 * invstd, 0.f);
  float t3 = fmaxf(o3 * invstd, 0.f);
  ushort4 hb;
  hb.x = f2bf(t0); hb.y = f2bf(t1); hb.z = f2bf(t2); hb.w = f2bf(t3);
  *(ushort4*)&h2b[(size_t)n * 256 + c0] = hb;
  if (Wqe_next){
    float4 g0 = *(const float4*)&Wqe_next[(c0 + 0) * 4];
    float4 g1 = *(const float4*)&Wqe_next[(c0 + 1) * 4];
    float4 g2 = *(const float4*)&Wqe_next[(c0 + 2) * 4];
    float4 g3 = *(const float4*)&Wqe_next[(c0 + 3) * 4];
    float s0 = t0 * g0.x + t1 * g1.x + t2 * g2.x + t3 * g3.x;
    float s1 = t0 * g0.y + t1 * g1.y + t2 * g2.y + t3 * g3.y;
    float s2 = t0 * g0.z + t1 * g1.z + t2 * g2.z + t3 * g3.z;
    float s3 = t0 * g0.w + t1 * g1.w + t2 * g2.w + t3 * g3.w;
    s0 = wred_sum(s0); s1 = wred_sum(s1); s2 = wred_sum(s2); s3 = wred_sum(s3);
    if (lane == 0){
      float4 bq4 = *(const float4*)bqe_next;
      float4 o; o.x = s0 + bq4.x; o.y = s1 + bq4.y; o.z = s2 + bq4.z; o.w = s3 + bq4.w;
      *(float4*)&qwe_out[(size_t)n * 4] = o;
    }
  }
}

// ---------------- launch ----------------
extern "C" void kernel_launch(void* const* d_in, const int* in_sizes, int n_in,
                              void* d_out, int out_size, void* d_ws, size_t ws_size,
                              hipStream_t stream)
{
  const float* x     = (const float*)d_in[0];
  const int*   eidx  = (const int*)d_in[1];
  const float* Wq1 = (const float*)d_in[3];  const float* bq1 = (const float*)d_in[4];
  const float* Wk1 = (const float*)d_in[5];  const float* bk1 = (const float*)d_in[6];
  const float* Wv1 = (const float*)d_in[7];  const float* bv1 = (const float*)d_in[8];
  const float* We1 = (const float*)d_in[9];
  const float* Ws1 = (const float*)d_in[10]; const float* bs1 = (const float*)d_in[11];
  const float* Wq = (const float*)d_in[12];  const float* bq = (const float*)d_in[13];
  const float* Wk = (const float*)d_in[14];  const float* bk = (const float*)d_in[15];
  const float* Wv = (const float*)d_in[16];  const float* bv = (const float*)d_in[17];
  const float* We = (const float*)d_in[18];
  const float* Ws = (const float*)d_in[19];  const float* bs = (const float*)d_in[20];
  const float* Wl = (const float*)d_in[21];  const float* bl = (const float*)d_in[22];
  const float* scale = (const float*)d_in[23];
  (void)n_in; (void)ws_size;

  int N = in_sizes[0] / 16;
  int E = in_sizes[2] / 4;
  int Mpad = (N + 127) & ~127;
  float* out = (float*)d_out;
  (void)out_size;

  char* p = (char*)d_ws;
  auto alloc = [&](size_t bytes) -> char* {
    char* r = p; p += (bytes + 255) & ~(size_t)255; return r;
  };
  float* hx   = (float*)alloc((size_t)N * 16 * 4);
  float* ea   = (float*)alloc((size_t)E * 4 * 4);
  _Float16* hh = (_Float16*)alloc((size_t)N * 256 * 2);
  unsigned short* h2b = (unsigned short*)alloc((size_t)Mpad * 256 * 2);
  _Float16* qkvh = (_Float16*)alloc((size_t)N * 768 * 2);
  _Float16* slh  = (_Float16*)alloc((size_t)N * 256 * 2);
  float* qwe  = (float*)alloc((size_t)N * 4 * 4);
  float* ea_csr = (float*)alloc((size_t)E * 4 * 4);
  int* src_csr  = (int*)alloc((size_t)E * 4);
  unsigned short* Wp  = (unsigned short*)alloc((size_t)15 * 1024 * 256 * 2);
  float* bp   = (float*)alloc((size_t)15 * 1024 * 4);
  float* Wqe  = (float*)alloc((size_t)15 * 256 * 4 * 4);
  float* bqe  = (float*)alloc((size_t)15 * 4 * 4);
  float* wlsc = (float*)alloc(257 * 4);
  int* counts  = (int*)alloc((size_t)N * 4);
  int* cursor  = (int*)alloc((size_t)N * 4);
  int* row_ptr = (int*)alloc(((size_t)N + 1) * 4);

  const int* srcp = eidx;
  const int* dstp = eidx + E;

  int nx = N * 16, ne = E * 4;
  int big = nx > ne ? nx : ne;
  if (E > big) big = E;

  hipMemsetAsync(counts, 0, (size_t)N * 4, stream);
  prep_hist_kernel<<<(big + 255) / 256, 256, 0, stream>>>(
      x, (const float*)d_in[2], dstp, hx, ea, counts, nx, ne, E);
  scan_kernel<<<1, 1024, 0, stream>>>(counts, row_ptr, cursor, N);
  scatter_kernel<<<(E + 255) / 256, 256, 0, stream>>>(srcp, dstp, ea, cursor,
                                                      src_csr, ea_csr, E);
  pack_w_kernel<<<dim3(8, 32, 15), 256, 0, stream>>>(Wq, Wk, Wv, Ws, Wp);
  pack_wqe_kernel<<<16, 256, 0, stream>>>(Wq, We, bq, Wqe, bqe,
                                          bk, bv, bs, bp, Wl, bl, scale, wlsc);

  int agg_blocks = (N + 7) / 8;

  // conv1
  gemm1_kernel<<<(N + 63) / 64, 256, 0, stream>>>(hx, Wq1, Wk1, Wv1, Ws1,
                                                  bq1, bk1, bv1, bs1, qkvh, slh, N);
  qwe1_kernel<<<(N + 3) / 4, 256, 0, stream>>>(qkvh, We1, qwe, N);
  agg_kernel<<<agg_blocks, 512, 0, stream>>>(qkvh, slh, qwe, ea_csr, src_csr, We1,
                                             Wqe, bqe, row_ptr,
                                             hh, hh, h2b, qwe, wlsc, out, 0, 0, N);

  // 15 residual blocks
  for (int l = 0; l < 15; l++){
    gemm_mfma_kernel<<<dim3(Mpad / 128, 8), 256, 0, stream>>>(
        h2b, Wp + (size_t)l * 262144, bp + (size_t)l * 1024, qkvh, slh, N);
    int last = (l == 14);
    const float* wqe_n = (l < 14) ? (Wqe + (size_t)(l + 1) * 1024) : nullptr;
    const float* bqe_n = (l < 14) ? (bqe + (size_t)(l + 1) * 4) : nullptr;
    agg_kernel<<<agg_blocks, 512, 0, stream>>>(qkvh, slh, qwe, ea_csr, src_csr,
                                               We + (size_t)l * 1024,
                                               wqe_n, bqe_n, row_ptr,
                                               hh, hh, h2b, qwe, wlsc, out, 1, last, N);
  }
}